// Round 9
// baseline (227.909 us; speedup 1.0000x reference)
//
#include <hip/hip_runtime.h>

// ---------------------------------------------------------------------------
// Round 24 = Round 23 (pt=3 phase-split, 92.5us) minus the last two leaks:
//  - residual ~7MB spill came from the chunk loop peak (x6a 48 + xd 24 +
//    acc5 24 + chf 12 + 8 w-frags 32 ~= 140 > 128). h4 stage now runs
//    per-pt (one pt's xd/acc5 live at a time: peak ~100).
//  - tanh's input scale 2*log2(e) is linear -> baked into W_h2/b_h2/
//    W_h4/b_h4 at setup. tanh_fast loses its v_mul: -156 VALU ops/lane
//    (~5% of the VALU floor). Same relative f16 quantization error.
//  - Everything else identical to R23.
// ---------------------------------------------------------------------------

#define IW 384
#define HW (384 * 384)           // 147456
#define NPIX (4 * HW)            // 589824
#define MTILE 192
#define NBLK (NPIX / MTILE)      // 3072

#define TANH_SCALE 2.8853900817779268f   // 2*log2(e), baked into h2/h4 weights

typedef _Float16 half8 __attribute__((ext_vector_type(8)));
typedef __fp16 fp16x2 __attribute__((ext_vector_type(2)));
typedef __attribute__((ext_vector_type(4))) float f32x4;
typedef __attribute__((ext_vector_type(4))) unsigned int uint4_;

#define MFMAH(A, B, C) __builtin_amdgcn_mfma_f32_16x16x32_f16((A), (B), (C), 0, 0, 0)

// bias table offsets (dwords in ws)
#define BA   0
#define B1   64
#define B2   144
#define BEF  224
#define BD   240
#define B4   304
#define B5   432
#define BOUT 496
#define BIAS_TOT 512

// weight image segment offsets (shorts, after bias table). frag = 512 shorts.
#define W_A0   0
#define W_A1   2048
#define W_A2   4096
#define W_H1A  6144
#define W_H1B  8704
#define W_H2A  11264
#define W_H2B  13824
#define W_H2C  16384
#define W_EF   18944    // E: 6 frags hi/lo (kt-major), F: 4 frags at +3072
#define W_D    24064    // 8 frags hi/lo (nt-major)
#define W_H4C0 28160    // chunk c: h4 at 28160+c*4096
#define W_H5C0 30208    //          h5 at 30208+c*4096
#define W_OUT  44544
#define W_NI   45568    // negated identity: 4 frags (nt, kt=nt>>1 baked)
#define W_TOT  47616

// be / bf slots (dword offsets, after images): 16 entries each, zero-padded
#define STG_BE  24320
#define STG_BF  24336

__device__ __forceinline__ float lrelu(float v) { return fmaxf(v, 0.01f * v); }

#if __has_builtin(__builtin_amdgcn_exp2f)
#define EXP2F __builtin_amdgcn_exp2f
#else
#define EXP2F __builtin_exp2f
#endif

// input pre-scaled by 2*log2(e) (baked into weights): tanh = 1 - 2/(2^v + 1)
__device__ __forceinline__ float tanh_fast(float v) {
    float e = EXP2F(v);
    return __builtin_fmaf(-2.0f, __builtin_amdgcn_rcpf(e + 1.0f), 1.0f);
}

__device__ __forceinline__ unsigned short f2h_bits(float v) {
    union { _Float16 h; unsigned short s; } u; u.h = (_Float16)v; return u.s;
}
__device__ __forceinline__ float h2f_bits(unsigned short s) {
    union { _Float16 h; unsigned short s; } u; u.s = s; return (float)u.h;
}
__device__ __forceinline__ unsigned packh2(float a, float b) {
    union { fp16x2 h; unsigned u; } u;
    u.h = __builtin_amdgcn_cvt_pkrtz(a, b);
    return u.u;
}

// deep-pipelined global->LDS staging: float4 x unroll-4
__device__ __forceinline__ void stage(float* dst, const float* __restrict__ src,
                                      int n, int tid) {
    int n4 = n >> 2;
    float4* d = (float4*)dst;
    const float4* s = (const float4*)src;
#pragma unroll 4
    for (int i = tid; i < n4; i += 256) d[i] = s[i];
    for (int i = (n4 << 2) + tid; i < n; i += 256) dst[i] = src[i];
}

// ---------------------------------------------------------------------------
// setup_all: 75 independent blocks x 256 threads.
// R23 + TANH_SCALE baked into W_h2 (lay 2), W_h4 (lay 6), b_h2, b_h4.
// ---------------------------------------------------------------------------
__global__ __launch_bounds__(256) void setup_all(
    const float* __restrict__ W_input, const float* __restrict__ b_input,
    const float* __restrict__ W_h1,  const float* __restrict__ b_h1,
    const float* __restrict__ W_h2,  const float* __restrict__ b_h2,
    const float* __restrict__ W_h3,  const float* __restrict__ b_h3,
    const float* __restrict__ W_h4,  const float* __restrict__ b_h4,
    const float* __restrict__ W_h5,  const float* __restrict__ b_h5,
    const float* __restrict__ W_out, const float* __restrict__ b_out,
    const float* __restrict__ W_e1,  const float* __restrict__ b_e1,
    const float* __restrict__ W_e2,  const float* __restrict__ b_e2,
    const float* __restrict__ W_e3,  const float* __restrict__ b_e3,
    const float* __restrict__ W_f1,  const float* __restrict__ b_f1,
    const float* __restrict__ W_f2,  const float* __restrict__ b_f2,
    const float* __restrict__ W_f3,  const float* __restrict__ b_f3,
    const float* __restrict__ W_d1,  const float* __restrict__ b_d1,
    const float* __restrict__ W_d2,  const float* __restrict__ b_d2,
    const float* __restrict__ W_d3,  const float* __restrict__ b_d3,
    float* __restrict__ ws)
{
    const int tid = threadIdx.x;
    const int NT = 256;
    short* wimg = (short*)(ws + BIAS_TOT);

    if (blockIdx.x < 71) {
        const int soff[17] = {W_A0,W_A1,W_A2, W_H1A,W_H1B, W_H2A,W_H2B,W_H2C,
                              W_H4C0,W_H5C0, W_H4C0+4096,W_H5C0+4096,
                              W_H4C0+8192,W_H5C0+8192, W_H4C0+12288,W_H5C0+12288,
                              W_OUT};
        const int slay[17] = {0,0,0, 1,1, 2,2,2, 6,7, 6,7, 6,7, 6,7, 8};
        const int sNT[17]  = {4,4,4, 5,5, 5,5,5, 2,4, 2,4, 2,4, 2,4, 1};
        const int sKTS[17] = {1,1,1, 1,1, 1,1,1, 2,1, 2,1, 2,1, 2,1, 2};
        const int snb[17]  = {0,0,0, 0,0, 0,0,0, 0,0, 32,0, 64,0, 96,0, 0};
        const int skb[17]  = {0,32,64, 0,32, 0,32,64, 0,0, 0,32, 0,64, 0,96, 0};

        int seg = 0, local = blockIdx.x;
        while (seg < 16 && local >= sNT[seg] * sKTS[seg]) { local -= sNT[seg] * sKTS[seg]; seg++; }
        const int kts = sKTS[seg];
        const int kt = local % kts, nt = local / kts;
        const int lay = slay[seg];
        short* dst = wimg + soff[seg] + local * 512;

#pragma unroll
        for (int t = 0; t < 2; t++) {
            int idx = tid + t * 256;
            int j = idx & 7, lane = idx >> 3;
            // sigma slot for layers consumed from MFMA C-frags; identity for A.
            int slot = (lay == 0) ? ((lane >> 4) * 8 + j)
                                  : (4 * (lane >> 4) + (j & 3) + 16 * (j >> 2));
            int n = snb[seg] + nt * 16 + (lane & 15);
            int k = skb[seg] + kt * 32 + slot;
            float v = 0.0f;
            switch (lay) {
                case 0: if (n < 50  && k < 75)  v = W_input[n * 75 + k]; break;
                case 1: if (n < 75  && k < 50)  v = W_h1[n * 50 + k]; break;
                case 2: if (n < 75  && k < 75)  v = W_h2[n * 75 + k] * TANH_SCALE; break;
                case 6: if (n < 125 && k < 50)  v = W_h4[n * 50 + k] * TANH_SCALE; break;
                case 7: if (n < 50  && k < 125) v = W_h5[n * 125 + k]; break;
                case 8: if (n < 3   && k < 50)  v = W_out[n * 50 + k]; break;
            }
            dst[idx] = (short)f2h_bits(v);
        }
        return;
    }

    if (blockIdx.x == 74) {
        for (int i = tid; i < BIAS_TOT; i += NT) {
            if (i >= BD && i < B4) continue;
            float v = 0.0f;
            if (i < B1)        { int o = i - BA;   if (o < 50)  v = b_input[o]; }
            else if (i < B2)   { int o = i - B1;   if (o < 75)  v = b_h1[o]; }
            else if (i < BEF)  { int o = i - B2;   if (o < 75)  v = b_h2[o] * TANH_SCALE; }
            else if (i < BD)   { v = 0.0f; }
            else if (i < B5)   { int o = i - B4;   if (o < 125) v = b_h4[o] * TANH_SCALE; }
            else if (i < BOUT) { int o = i - B5;   if (o < 50)  v = b_h5[o]; }
            else               { int o = i - BOUT; if (o < 3)   v = b_out[o]; }
            ws[i] = v;
        }
        for (int i = tid; i < 2048; i += NT) {
            int j = i & 7, lane = (i >> 3) & 63, nt = i >> 9;
            int n = nt * 16 + (lane & 15);
            int k = (nt >> 1) * 32 + 4 * (lane >> 4) + (j & 3) + 16 * (j >> 2);
            wimg[W_NI + i] = (short)f2h_bits(k == n ? -1.0f : 0.0f);
        }
        return;
    }

    __shared__ __align__(16) float A[17500];
    __shared__ float B[675];
    __shared__ float C[256];
    __shared__ float Dd[256];
    __shared__ float Es[256];
    __shared__ float S[232];

    if (blockIdx.x == 71) {
        // ================= E chain =================
        stage(A, W_e2, 16875, tid);
        for (int i = tid; i < 225; i += NT) { Es[i] = W_e3[i]; C[i] = b_e1[i]; }
        __syncthreads();
        for (int o = tid; o < 675; o += NT) {
            int r = o / 225, c = o % 225;
            float s0 = 0.f, s1 = 0.f, s2 = 0.f;
#pragma unroll
            for (int t = 0; t < 75; t += 3) {
                s0 += Es[r * 75 + t]     * A[t * 225 + c];
                s1 += Es[r * 75 + t + 1] * A[(t + 1) * 225 + c];
                s2 += Es[r * 75 + t + 2] * A[(t + 2) * 225 + c];
            }
            B[o] = s0 + s1 + s2;
        }
        for (int o = tid; o < 75; o += NT) {
            float s0 = 0.f, s1 = 0.f, s2 = 0.f;
#pragma unroll
            for (int t = 0; t < 225; t += 3) {
                s0 += A[o * 225 + t]     * C[t];
                s1 += A[o * 225 + t + 1] * C[t + 1];
                s2 += A[o * 225 + t + 2] * C[t + 2];
            }
            Dd[o] = b_e2[o] + s0 + s1 + s2;
        }
        __syncthreads();
        stage(A, W_e1, 16875, tid);
        __syncthreads();
        for (int o = tid; o < 225; o += NT) {
            int r = o / 75, c = o % 75;
            float s0 = 0.f, s1 = 0.f, s2 = 0.f;
#pragma unroll
            for (int t = 0; t < 225; t += 3) {
                s0 += B[r * 225 + t]     * A[t * 75 + c];
                s1 += B[r * 225 + t + 1] * A[(t + 1) * 75 + c];
                s2 += B[r * 225 + t + 2] * A[(t + 2) * 75 + c];
            }
            S[o] = s0 + s1 + s2;
        }
        for (int o = tid; o < 16; o += NT) {
            float s = 0.0f;
            if (o < 3) {
                s = b_e3[o];
                for (int t = 0; t < 75; t++) s += Es[o * 75 + t] * Dd[t];
            }
            ws[STG_BE + o] = s;
        }
        __syncthreads();
        for (int i = tid; i < 3072; i += NT) {
            int j = i & 7, lane = (i >> 3) & 63, frag = i >> 9, pl = frag & 1, kt = frag >> 1;
            int n = lane & 15;
            int k = kt * 32 + 4 * (lane >> 4) + (j & 3) + 16 * (j >> 2);
            float v = (n < 3 && k < 75) ? S[n * 75 + k] : 0.0f;
            float hi = h2f_bits(f2h_bits(v));
            wimg[W_EF + i] = (short)(pl ? f2h_bits(v - hi) : f2h_bits(v));
        }
    } else if (blockIdx.x == 72) {
        // ================= F chain =================
        stage(A,        W_f2, 7500, tid);
        stage(A + 7500, W_f1, 7500, tid);
        for (int i = tid; i < 150; i += NT) { Es[i] = W_f3[i]; C[i] = b_f1[i]; }
        __syncthreads();
        for (int o = tid; o < 450; o += NT) {
            int r = o / 150, c = o % 150;
            float s0 = 0.f, s1 = 0.f;
#pragma unroll
            for (int t = 0; t < 50; t += 2) {
                s0 += Es[r * 50 + t]     * A[t * 150 + c];
                s1 += Es[r * 50 + t + 1] * A[(t + 1) * 150 + c];
            }
            B[o] = s0 + s1;
        }
        for (int o = tid; o < 50; o += NT) {
            float s0 = 0.f, s1 = 0.f;
#pragma unroll
            for (int t = 0; t < 150; t += 2) {
                s0 += A[o * 150 + t]     * C[t];
                s1 += A[o * 150 + t + 1] * C[t + 1];
            }
            Dd[o] = b_f2[o] + s0 + s1;
        }
        __syncthreads();
        for (int o = tid; o < 150; o += NT) {
            int r = o / 50, c = o % 50;
            float s0 = 0.f, s1 = 0.f;
#pragma unroll
            for (int t = 0; t < 150; t += 2) {
                s0 += B[r * 150 + t]     * A[7500 + t * 50 + c];
                s1 += B[r * 150 + t + 1] * A[7500 + (t + 1) * 50 + c];
            }
            S[o] = s0 + s1;
        }
        for (int o = tid; o < 16; o += NT) {
            float s = 0.0f;
            if (o < 3) {
                s = b_f3[o];
                for (int t = 0; t < 50; t++) s += Es[o * 50 + t] * Dd[t];
            }
            ws[STG_BF + o] = s;
        }
        __syncthreads();
        for (int i = tid; i < 2048; i += NT) {
            int j = i & 7, lane = (i >> 3) & 63, frag = i >> 9, pl = frag & 1, kt = frag >> 1;
            int n = lane & 15;
            int k = kt * 32 + 4 * (lane >> 4) + (j & 3) + 16 * (j >> 2);
            float v = (n < 3 && k < 50) ? S[n * 50 + k] : 0.0f;
            float hi = h2f_bits(f2h_bits(v));
            wimg[W_EF + 3072 + i] = (short)(pl ? f2h_bits(v - hi) : f2h_bits(v));
        }
    } else {
        // ================= D chain =================
        stage(A,         W_d2, 7500, tid);
        stage(A + 7500,  W_d3, 7500, tid);
        stage(A + 15000, W_h3, 2500, tid);
        for (int i = tid; i < 150; i += NT) Es[i] = W_d1[i];
        for (int i = tid; i < 50;  i += NT) C[i] = b_d1[i];
        __syncthreads();
        for (int o = tid; o < 450; o += NT) {
            int r = o / 3, c = o % 3;
            float s0 = 0.f, s1 = 0.f;
#pragma unroll
            for (int t = 0; t < 50; t += 2) {
                s0 += A[r * 50 + t]     * Es[t * 3 + c];
                s1 += A[r * 50 + t + 1] * Es[(t + 1) * 3 + c];
            }
            B[o] = s0 + s1;
        }
        for (int o = tid; o < 150; o += NT) {
            float s0 = 0.f, s1 = 0.f;
#pragma unroll
            for (int t = 0; t < 50; t += 2) {
                s0 += A[o * 50 + t]     * C[t];
                s1 += A[o * 50 + t + 1] * C[t + 1];
            }
            Dd[o] = b_d2[o] + s0 + s1;
        }
        __syncthreads();
        for (int o = tid; o < 150; o += NT) {
            int r = o / 3, c = o % 3;
            float s0 = 0.f, s1 = 0.f;
#pragma unroll
            for (int t = 0; t < 150; t += 2) {
                s0 += A[7500 + r * 150 + t]     * B[t * 3 + c];
                s1 += A[7500 + r * 150 + t + 1] * B[(t + 1) * 3 + c];
            }
            Es[o] = s0 + s1;
        }
        for (int o = tid; o < 50; o += NT) {
            float s0 = 0.f, s1 = 0.f;
#pragma unroll
            for (int t = 0; t < 150; t += 2) {
                s0 += A[7500 + o * 150 + t]     * Dd[t];
                s1 += A[7500 + o * 150 + t + 1] * Dd[t + 1];
            }
            C[o] = b_d3[o] + s0 + s1;
        }
        __syncthreads();
        for (int o = tid; o < 150; o += NT) {
            int r = o / 3, c = o % 3;
            float s0 = 0.f, s1 = 0.f;
#pragma unroll
            for (int t = 0; t < 50; t += 2) {
                s0 += A[15000 + r * 50 + t]     * Es[t * 3 + c];
                s1 += A[15000 + r * 50 + t + 1] * Es[(t + 1) * 3 + c];
            }
            S[o] = s0 + s1;
        }
        for (int o = tid; o < 64; o += NT) {
            float v = 0.0f;
            if (o < 50) {
                float s0 = 0.f, s1 = 0.f;
#pragma unroll
                for (int t = 0; t < 50; t += 2) {
                    s0 += A[15000 + o * 50 + t]     * C[t];
                    s1 += A[15000 + o * 50 + t + 1] * C[t + 1];
                }
                v = b_h3[o] + s0 + s1;
            }
            ws[BD + o] = v;
        }
        __syncthreads();
        for (int i = tid; i < 4096; i += NT) {
            int j = i & 7, lane = (i >> 3) & 63, frag = i >> 9, pl = frag & 1, nt = frag >> 1;
            int n = nt * 16 + (lane & 15);
            int k = 4 * (lane >> 4) + (j & 3) + 16 * (j >> 2);
            float v = (n < 50 && k < 3) ? S[n * 3 + k] : 0.0f;
            float hi = h2f_bits(f2h_bits(v));
            wimg[W_D + i] = (short)(pl ? f2h_bits(v - hi) : f2h_bits(v));
        }
    }
}

// ---------------------------------------------------------------------------
// main kernel helpers
// ---------------------------------------------------------------------------
__device__ __forceinline__ half8 gfragH(const short* __restrict__ wl, int off) {
    return *(const half8*)(wl + off);
}

// Build next-layer B-frag from two C-frags of this lane (sigma k-ordering).
__device__ __forceinline__ half8 packB(f32x4 lo, f32x4 hi) {
    union { unsigned u32[4]; half8 v; } u;
    u.u32[0] = packh2(lo[0], lo[1]);
    u.u32[1] = packh2(lo[2], lo[3]);
    u.u32[2] = packh2(hi[0], hi[1]);
    u.u32[3] = packh2(hi[2], hi[3]);
    return u.v;
}
__device__ __forceinline__ half8 packB1(f32x4 lo) {   // upper 16-neuron half absent
    union { unsigned u32[4]; half8 v; } u;
    u.u32[0] = packh2(lo[0], lo[1]);
    u.u32[1] = packh2(lo[2], lo[3]);
    u.u32[2] = 0u; u.u32[3] = 0u;
    return u.v;
}

__device__ __forceinline__ void st16(unsigned int* p, half8 v) {
    union { half8 h; uint4_ u; } c; c.h = v;
    *(uint4_*)p = c.u;
}
__device__ __forceinline__ half8 ld16(const unsigned int* p) {
    union { half8 h; uint4_ u; } c; c.u = *(const uint4_*)p;
    return c.h;
}

__device__ __forceinline__ f32x4 lrelu4(f32x4 v) {
    v[0] = lrelu(v[0]); v[1] = lrelu(v[1]); v[2] = lrelu(v[2]); v[3] = lrelu(v[3]);
    return v;
}
__device__ __forceinline__ f32x4 tanh4(f32x4 v) {
    v[0] = tanh_fast(v[0]); v[1] = tanh_fast(v[1]);
    v[2] = tanh_fast(v[2]); v[3] = tanh_fast(v[3]);
    return v;
}

// ---------------------------------------------------------------------------
// main fused kernel: 48 pixels/wave at (256,4). Layers A/h1 in mt-pairs;
// h2 fused into EF; h4 stage per-pt (chunk-loop peak ~100 regs). x1f parked
// in LDS; xdf parked into freed slots. No barriers after the prologue.
// ---------------------------------------------------------------------------
__global__ __launch_bounds__(256, 4) void fused_mfma(
    const float* __restrict__ xin,
    const float* __restrict__ ws,
    float* __restrict__ out)
{
    __shared__ float patch[2940];          // 3ch x 5r x 196
    __shared__ int stab[96];
    __shared__ unsigned int x1buf[6144];   // 24KB: [wv][kt*3+pt][lane] 16B slots

    const int tid = threadIdx.x;
    const int wv = tid >> 6;
    const int lane = tid & 63;
    const int qd = lane >> 4;
    const int mcol = lane & 15;
    const short* __restrict__ wl = (const short*)(ws + BIAS_TOT) + lane * 8;

    const int g0 = blockIdx.x * MTILE;
    const int bb = g0 / HW;
    const int p0 = g0 - bb * HW;
    const int yb = p0 / IW;
    const int xblk = p0 - yb * IW;
    const float* __restrict__ xb = xin + bb * 3 * HW;

    unsigned int* xpark = x1buf + wv * 1536 + lane * 4;   // +kt*768 +pt*256

    for (int e = tid; e < 2940; e += 256) {
        int cr = e / 196;
        int i  = e - cr * 196;
        int c  = cr / 5, r = cr - c * 5;
        int ty = yb + r - 2; ty = ty < 0 ? -ty : ty; ty = (766 - ty) < ty ? 766 - ty : ty;
        int tx = xblk - 2 + i; tx = tx < 0 ? -tx : tx; tx = (766 - tx) < tx ? 766 - tx : tx;
        patch[cr * 196 + i] = xb[c * HW + ty * IW + tx];
    }
    if (tid < 96) {
        int v = 0;
        if (tid < 75) {
            int c = tid / 25, rem = tid - 25 * c;
            int rr = rem / 5, ss = rem - 5 * rr;
            v = (c * 5 + rr) * 196 + ss;
        }
        stab[tid] = v;
    }
    __syncthreads();

    // build sw B-fragments from LDS patch (lane&15 = pixel, identity k-order).
    half8 swf[3][3];
    {
        int st[3][8];
#pragma unroll
        for (int kt = 0; kt < 3; kt++)
#pragma unroll
            for (int j = 0; j < 8; j++)
                st[kt][j] = stab[kt * 32 + qd * 8 + j];
#pragma unroll
        for (int pt = 0; pt < 3; pt++) {
            const int xloc = wv * 48 + pt * 16 + mcol;
#pragma unroll
            for (int kt = 0; kt < 3; kt++) {
                union { unsigned u32[4]; half8 v; } u;
#pragma unroll
                for (int jj = 0; jj < 8; jj += 2) {
                    float v0 = patch[st[kt][jj]     + xloc];
                    float v1 = patch[st[kt][jj + 1] + xloc];
                    if (kt == 2) {
                        int qq0 = 64 + qd * 8 + jj;
                        v0 = (qq0     < 75) ? v0 : 0.0f;
                        v1 = (qq0 + 1 < 75) ? v1 : 0.0f;
                    }
                    u.u32[jj >> 1] = packh2(v0, v1);
                }
                swf[kt][pt] = u.v;
            }
        }
    }
    // patch is never written again; x1buf is lane-private -> no second barrier.

    // ===== layer A =====  (50x75 -> mt-pairs {0,1},{2,3}; 3 kt)
    half8 x1f[2][3];
#pragma unroll
    for (int g = 0; g < 2; g++) {
        const short* wlg = wl;
        asm volatile("" : "+v"(wlg));      // fence: no cross-group load hoist
        f32x4 acc[2][3];
#pragma unroll
        for (int m = 0; m < 2; m++) {
            f32x4 b = *(const f32x4*)(ws + BA + (2 * g + m) * 16 + qd * 4);
            acc[m][0] = b; acc[m][1] = b; acc[m][2] = b;
        }
#pragma unroll
        for (int kt = 0; kt < 3; kt++)
#pragma unroll
            for (int m = 0; m < 2; m++) {
                half8 w = gfragH(wlg, W_A0 + kt * 2048 + (2 * g + m) * 512);
#pragma unroll
                for (int pt = 0; pt < 3; pt++)
                    acc[m][pt] = MFMAH(w, swf[kt][pt], acc[m][pt]);
            }
#pragma unroll
        for (int pt = 0; pt < 3; pt++) {
            x1f[g][pt] = packB(acc[0][pt], acc[1][pt]);
            st16(xpark + g * 768 + pt * 256, x1f[g][pt]);   // park for EF/NI
        }
    }

    // ===== h1 =====  (75x50 -> mt-pairs {0,1},{2,3} + tail 4; 2 kt), lrelu
    half8 x2f[3][3];
#pragma unroll
    for (int g = 0; g < 2; g++) {
        const short* wlg = wl;
        asm volatile("" : "+v"(wlg));
        f32x4 acc[2][3];
#pragma unroll
        for (int m = 0; m < 2; m++) {
            f32x4 b = *(const f32x4*)(ws + B1 + (2 * g + m) * 16 + qd * 4);
            acc[m][0] = b; acc[m][1] = b; acc[m][2] = b;
        }
#pragma unroll
        for (int kt = 0; kt < 2; kt++)
#pragma unroll
            for (int m = 0; m < 2; m++) {
                half8 w = gfragH(wlg, W_H1A + kt * 2560 + (2 * g + m) * 512);
#pragma unroll
                for (int pt = 0; pt < 3; pt++)
                    acc[m][pt] = MFMAH(w, x1f[kt][pt], acc[m][pt]);
            }
#pragma unroll
        for (int pt = 0; pt < 3; pt++)
            x2f[g][pt] = packB(lrelu4(acc[0][pt]), lrelu4(acc[1][pt]));
    }
    {   // tail mt=4  (x1f regs die here)
        const short* wlg = wl;
        asm volatile("" : "+v"(wlg));
        f32x4 acc[3];
        {
            f32x4 b = *(const f32x4*)(ws + B1 + 4 * 16 + qd * 4);
            acc[0] = b; acc[1] = b; acc[2] = b;
        }
#pragma unroll
        for (int kt = 0; kt < 2; kt++) {
            half8 w = gfragH(wlg, W_H1A + kt * 2560 + 4 * 512);
#pragma unroll
            for (int pt = 0; pt < 3; pt++)
                acc[pt] = MFMAH(w, x1f[kt][pt], acc[pt]);
        }
#pragma unroll
        for (int pt = 0; pt < 3; pt++)
            x2f[2][pt] = packB1(lrelu4(acc[pt]));
    }

    // ===== h2 fused into EF =====  each x3f group consumed immediately.
    f32x4 accEF[3];
    {
        f32x4 be = *(const f32x4*)(ws + STG_BE + qd * 4);
        f32x4 bf = *(const f32x4*)(ws + STG_BF + qd * 4);
        f32x4 b = be + bf;
        accEF[0] = b; accEF[1] = b; accEF[2] = b;
    }
#pragma unroll
    for (int g = 0; g < 2; g++) {      // h2 mt-pairs {0,1},{2,3} -> E kt=g
        const short* wlg = wl;
        asm volatile("" : "+v"(wlg));
        f32x4 acc[2][3];
#pragma unroll
        for (int m = 0; m < 2; m++) {
            f32x4 b = *(const f32x4*)(ws + B2 + (2 * g + m) * 16 + qd * 4);
            acc[m][0] = b; acc[m][1] = b; acc[m][2] = b;
        }
#pragma unroll
        for (int kt = 0; kt < 3; kt++)
#pragma unroll
            for (int m = 0; m < 2; m++) {
                half8 w = gfragH(wlg, W_H2A + kt * 2560 + (2 * g + m) * 512);
#pragma unroll
                for (int pt = 0; pt < 3; pt++)
                    acc[m][pt] = MFMAH(w, x2f[kt][pt], acc[m][pt]);
            }
        half8 wh = gfragH(wlg, W_EF + g * 1024);
        half8 wo = gfragH(wlg, W_EF + g * 1024 + 512);
#pragma unroll
        for (int pt = 0; pt < 3; pt++) {
            half8 t = packB(tanh4(acc[0][pt]), tanh4(acc[1][pt]));
            accEF[pt] = MFMAH(wh, t, accEF[pt]);
            accEF[pt] = MFMAH(wo, t, accEF[pt]);
        }
    }
    {   // h2 tail mt=4 -> E kt=2  (x2f dies here)
        const short* wlg = wl;
        asm volatile("" : "+v"(wlg));
        f32x4 acc[3];
        {
            f32x4 b = *(const f32x4*)(ws + B2 + 4 * 16 + qd * 4);
            acc[0] = b; acc[1] = b; acc[2] = b;
        }
#pragma unroll
        for (int kt = 0; kt < 3; kt++) {
            half8 w = gfragH(wlg, W_H2A + kt * 2560 + 4 * 512);
#pragma unroll
            for (int pt = 0; pt < 3; pt++)
                acc[pt] = MFMAH(w, x2f[kt][pt], acc[pt]);
        }
        half8 wh = gfragH(wlg, W_EF + 2 * 1024);
        half8 wo = gfragH(wlg, W_EF + 2 * 1024 + 512);
#pragma unroll
        for (int pt = 0; pt < 3; pt++) {
            half8 t = packB1(tanh4(acc[pt]));
            accEF[pt] = MFMAH(wh, t, accEF[pt]);
            accEF[pt] = MFMAH(wo, t, accEF[pt]);
        }
    }
    // unpark x1f for the F part + NI (lane-local ds_read_b128 x6)
    half8 x1r[2][3];
#pragma unroll
    for (int kt = 0; kt < 2; kt++)
#pragma unroll
        for (int pt = 0; pt < 3; pt++)
            x1r[kt][pt] = ld16(xpark + kt * 768 + pt * 256);
#pragma unroll
    for (int kt = 0; kt < 2; kt++) {   // F part
        half8 wh = gfragH(wl, W_EF + 3072 + kt * 1024);
        half8 wo = gfragH(wl, W_EF + 3072 + kt * 1024 + 512);
#pragma unroll
        for (int pt = 0; pt < 3; pt++) {
            accEF[pt] = MFMAH(wh, x1r[kt][pt], accEF[pt]);
            accEF[pt] = MFMAH(wo, x1r[kt][pt], accEF[pt]);
        }
    }
    half8 x4f[3];
#pragma unroll
    for (int pt = 0; pt < 3; pt++)
        x4f[pt] = packB1(lrelu4(accEF[pt]));

    // ===== NI first: x6a init = b5 - x1 (x1r's LAST use; frees park slots)
    f32x4 x6a[4][3];
#pragma unroll
    for (int mt = 0; mt < 4; mt++) {
        f32x4 b = *(const f32x4*)(ws + B5 + mt * 16 + qd * 4);
        half8 nI = gfragH(wl, W_NI + mt * 512);
#pragma unroll
        for (int pt = 0; pt < 3; pt++)
            x6a[mt][pt] = MFMAH(nI, x1r[mt >> 1][pt], b);
    }

    // ===== D =====  two mt-halves; park xdf into the freed x1 slots
#pragma unroll
    for (int h = 0; h < 2; h++) {
        f32x4 accD[2][3];
#pragma unroll
        for (int m2 = 0; m2 < 2; m2++) {
            f32x4 b = *(const f32x4*)(ws + BD + (h * 2 + m2) * 16 + qd * 4);
            accD[m2][0] = b; accD[m2][1] = b; accD[m2][2] = b;
        }
#pragma unroll
        for (int m2 = 0; m2 < 2; m2++) {
            int mt = h * 2 + m2;
            half8 wh = gfragH(wl, W_D + mt * 1024);
            half8 wo = gfragH(wl, W_D + mt * 1024 + 512);
#pragma unroll
            for (int pt = 0; pt < 3; pt++) {
                accD[m2][pt] = MFMAH(wh, x4f[pt], accD[m2][pt]);
                accD[m2][pt] = MFMAH(wo, x4f[pt], accD[m2][pt]);
            }
        }
#pragma unroll
        for (int pt = 0; pt < 3; pt++)
            st16(xpark + h * 768 + pt * 256, packB(accD[0][pt], accD[1][pt]));
    }

    // ===== h4/h5 chunks: h4 per-pt (one pt's xd/acc live at a time) =====
#pragma unroll
    for (int c = 0; c < 4; c++) {
        half8 w40 = gfragH(wl, W_H4C0 + c * 4096 + 0 * 512);  // mt2=0,kt=0
        half8 w41 = gfragH(wl, W_H4C0 + c * 4096 + 1 * 512);  // mt2=0,kt=1
        half8 w42 = gfragH(wl, W_H4C0 + c * 4096 + 2 * 512);  // mt2=1,kt=0
        half8 w43 = gfragH(wl, W_H4C0 + c * 4096 + 3 * 512);  // mt2=1,kt=1
        half8 chf[3];
#pragma unroll
        for (int pt = 0; pt < 3; pt++) {
            const unsigned int* xr = xpark;
            asm volatile("" : "+v"(xr));   // opaque: block LICM hoist
            half8 xd0 = ld16(xr + pt * 256);
            half8 xd1 = ld16(xr + 768 + pt * 256);
            f32x4 a0 = *(const f32x4*)(ws + B4 + c * 32 + qd * 4);
            f32x4 a1 = *(const f32x4*)(ws + B4 + c * 32 + 16 + qd * 4);
            a0 = MFMAH(w40, xd0, a0);
            a0 = MFMAH(w41, xd1, a0);
            a1 = MFMAH(w42, xd0, a1);
            a1 = MFMAH(w43, xd1, a1);
            chf[pt] = packB(tanh4(a0), tanh4(a1));
        }
#pragma unroll
        for (int mt = 0; mt < 4; mt++) {
            half8 w = gfragH(wl, W_H5C0 + c * 4096 + mt * 512);
#pragma unroll
            for (int pt = 0; pt < 3; pt++)
                x6a[mt][pt] = MFMAH(w, chf[pt], x6a[mt][pt]);
        }
    }

    // ===== out =====
    f32x4 accO[3];
    {
        f32x4 b = *(const f32x4*)(ws + BOUT + qd * 4);
        accO[0] = b; accO[1] = b; accO[2] = b;
    }
#pragma unroll
    for (int kt = 0; kt < 2; kt++) {
        half8 w = gfragH(wl, W_OUT + kt * 512);
#pragma unroll
        for (int pt = 0; pt < 3; pt++) {
            half8 x6f = packB(x6a[2 * kt][pt], x6a[2 * kt + 1][pt]);
            accO[pt] = MFMAH(w, x6f, accO[pt]);
        }
    }
    // C rows = output channels (0..2 live in qd==0, r<3); cols = pixels.
    if (qd == 0) {
#pragma unroll
        for (int pt = 0; pt < 3; pt++) {
            int p = p0 + wv * 48 + pt * 16 + mcol;
#pragma unroll
            for (int r = 0; r < 3; r++)
                out[(bb * 3 + r) * HW + p] = lrelu(accO[pt][r]);
        }
    }
}

extern "C" void kernel_launch(void* const* d_in, const int* in_sizes, int n_in,
                              void* d_out, int out_size, void* d_ws, size_t ws_size,
                              hipStream_t stream)
{
    const float* xin = (const float*)d_in[0];
    float* ws = (float*)d_ws;

    setup_all<<<75, 256, 0, stream>>>(
        (const float*)d_in[1],  (const float*)d_in[2],   // input
        (const float*)d_in[3],  (const float*)d_in[4],   // h1
        (const float*)d_in[5],  (const float*)d_in[6],   // h2
        (const float*)d_in[7],  (const float*)d_in[8],   // h3
        (const float*)d_in[9],  (const float*)d_in[10],  // h4
        (const float*)d_in[11], (const float*)d_in[12],  // h5
        (const float*)d_in[13], (const float*)d_in[14],  // out
        (const float*)d_in[15], (const float*)d_in[16],  // e1
        (const float*)d_in[17], (const float*)d_in[18],  // e2
        (const float*)d_in[19], (const float*)d_in[20],  // e3
        (const float*)d_in[21], (const float*)d_in[22],  // f1
        (const float*)d_in[23], (const float*)d_in[24],  // f2
        (const float*)d_in[25], (const float*)d_in[26],  // f3
        (const float*)d_in[27], (const float*)d_in[28],  // d1
        (const float*)d_in[29], (const float*)d_in[30],  // d2
        (const float*)d_in[31], (const float*)d_in[32],  // d3
        ws);

    fused_mfma<<<NBLK, 256, 0, stream>>>(xin, ws, (float*)d_out);
}

// Round 11
// 218.781 us; speedup vs baseline: 1.0417x; 1.0417x over previous
//
#include <hip/hip_runtime.h>

// ---------------------------------------------------------------------------
// Round 26 = union of the two best PASSING configurations:
//  - R23 main kernel verbatim (pt=3 phase-split, 3-pt-wide chunk loop,
//    92.5us, small ~9B/thread spill accepted - its ILP is worth more).
//  - R24's tanh bake (TANH_SCALE folded into W_h2/b_h2/W_h4/b_h4 at setup;
//    tanh_fast drops its v_mul). Proven safe in R24.
//  - R25's kt-interleaved chunk loop (crashed, SIGABRT, no counters) is
//    abandoned: both of its ingredients exist in passing kernels already.
// ---------------------------------------------------------------------------

#define IW 384
#define HW (384 * 384)           // 147456
#define NPIX (4 * HW)            // 589824
#define MTILE 192
#define NBLK (NPIX / MTILE)      // 3072

#define TANH_SCALE 2.8853900817779268f   // 2*log2(e), baked into h2/h4 weights

typedef _Float16 half8 __attribute__((ext_vector_type(8)));
typedef __fp16 fp16x2 __attribute__((ext_vector_type(2)));
typedef __attribute__((ext_vector_type(4))) float f32x4;
typedef __attribute__((ext_vector_type(4))) unsigned int uint4_;

#define MFMAH(A, B, C) __builtin_amdgcn_mfma_f32_16x16x32_f16((A), (B), (C), 0, 0, 0)

// bias table offsets (dwords in ws)
#define BA   0
#define B1   64
#define B2   144
#define BEF  224
#define BD   240
#define B4   304
#define B5   432
#define BOUT 496
#define BIAS_TOT 512

// weight image segment offsets (shorts, after bias table). frag = 512 shorts.
#define W_A0   0
#define W_A1   2048
#define W_A2   4096
#define W_H1A  6144
#define W_H1B  8704
#define W_H2A  11264
#define W_H2B  13824
#define W_H2C  16384
#define W_EF   18944    // E: 6 frags hi/lo (kt-major), F: 4 frags at +3072
#define W_D    24064    // 8 frags hi/lo (nt-major)
#define W_H4C0 28160    // chunk c: h4 at 28160+c*4096
#define W_H5C0 30208    //          h5 at 30208+c*4096
#define W_OUT  44544
#define W_NI   45568    // negated identity: 4 frags (nt, kt=nt>>1 baked)
#define W_TOT  47616

// be / bf slots (dword offsets, after images): 16 entries each, zero-padded
#define STG_BE  24320
#define STG_BF  24336

__device__ __forceinline__ float lrelu(float v) { return fmaxf(v, 0.01f * v); }

#if __has_builtin(__builtin_amdgcn_exp2f)
#define EXP2F __builtin_amdgcn_exp2f
#else
#define EXP2F __builtin_exp2f
#endif

// input pre-scaled by 2*log2(e) (baked into weights): tanh = 1 - 2/(2^v + 1)
__device__ __forceinline__ float tanh_fast(float v) {
    float e = EXP2F(v);
    return __builtin_fmaf(-2.0f, __builtin_amdgcn_rcpf(e + 1.0f), 1.0f);
}

__device__ __forceinline__ unsigned short f2h_bits(float v) {
    union { _Float16 h; unsigned short s; } u; u.h = (_Float16)v; return u.s;
}
__device__ __forceinline__ float h2f_bits(unsigned short s) {
    union { _Float16 h; unsigned short s; } u; u.s = s; return (float)u.h;
}
__device__ __forceinline__ unsigned packh2(float a, float b) {
    union { fp16x2 h; unsigned u; } u;
    u.h = __builtin_amdgcn_cvt_pkrtz(a, b);
    return u.u;
}

// deep-pipelined global->LDS staging: float4 x unroll-4
__device__ __forceinline__ void stage(float* dst, const float* __restrict__ src,
                                      int n, int tid) {
    int n4 = n >> 2;
    float4* d = (float4*)dst;
    const float4* s = (const float4*)src;
#pragma unroll 4
    for (int i = tid; i < n4; i += 256) d[i] = s[i];
    for (int i = (n4 << 2) + tid; i < n; i += 256) dst[i] = src[i];
}

// ---------------------------------------------------------------------------
// setup_all: 75 independent blocks x 256 threads.
// R23 + TANH_SCALE baked into W_h2 (lay 2), W_h4 (lay 6), b_h2, b_h4.
// ---------------------------------------------------------------------------
__global__ __launch_bounds__(256) void setup_all(
    const float* __restrict__ W_input, const float* __restrict__ b_input,
    const float* __restrict__ W_h1,  const float* __restrict__ b_h1,
    const float* __restrict__ W_h2,  const float* __restrict__ b_h2,
    const float* __restrict__ W_h3,  const float* __restrict__ b_h3,
    const float* __restrict__ W_h4,  const float* __restrict__ b_h4,
    const float* __restrict__ W_h5,  const float* __restrict__ b_h5,
    const float* __restrict__ W_out, const float* __restrict__ b_out,
    const float* __restrict__ W_e1,  const float* __restrict__ b_e1,
    const float* __restrict__ W_e2,  const float* __restrict__ b_e2,
    const float* __restrict__ W_e3,  const float* __restrict__ b_e3,
    const float* __restrict__ W_f1,  const float* __restrict__ b_f1,
    const float* __restrict__ W_f2,  const float* __restrict__ b_f2,
    const float* __restrict__ W_f3,  const float* __restrict__ b_f3,
    const float* __restrict__ W_d1,  const float* __restrict__ b_d1,
    const float* __restrict__ W_d2,  const float* __restrict__ b_d2,
    const float* __restrict__ W_d3,  const float* __restrict__ b_d3,
    float* __restrict__ ws)
{
    const int tid = threadIdx.x;
    const int NT = 256;
    short* wimg = (short*)(ws + BIAS_TOT);

    if (blockIdx.x < 71) {
        const int soff[17] = {W_A0,W_A1,W_A2, W_H1A,W_H1B, W_H2A,W_H2B,W_H2C,
                              W_H4C0,W_H5C0, W_H4C0+4096,W_H5C0+4096,
                              W_H4C0+8192,W_H5C0+8192, W_H4C0+12288,W_H5C0+12288,
                              W_OUT};
        const int slay[17] = {0,0,0, 1,1, 2,2,2, 6,7, 6,7, 6,7, 6,7, 8};
        const int sNT[17]  = {4,4,4, 5,5, 5,5,5, 2,4, 2,4, 2,4, 2,4, 1};
        const int sKTS[17] = {1,1,1, 1,1, 1,1,1, 2,1, 2,1, 2,1, 2,1, 2};
        const int snb[17]  = {0,0,0, 0,0, 0,0,0, 0,0, 32,0, 64,0, 96,0, 0};
        const int skb[17]  = {0,32,64, 0,32, 0,32,64, 0,0, 0,32, 0,64, 0,96, 0};

        int seg = 0, local = blockIdx.x;
        while (seg < 16 && local >= sNT[seg] * sKTS[seg]) { local -= sNT[seg] * sKTS[seg]; seg++; }
        const int kts = sKTS[seg];
        const int kt = local % kts, nt = local / kts;
        const int lay = slay[seg];
        short* dst = wimg + soff[seg] + local * 512;

#pragma unroll
        for (int t = 0; t < 2; t++) {
            int idx = tid + t * 256;
            int j = idx & 7, lane = idx >> 3;
            // sigma slot for layers consumed from MFMA C-frags; identity for A.
            int slot = (lay == 0) ? ((lane >> 4) * 8 + j)
                                  : (4 * (lane >> 4) + (j & 3) + 16 * (j >> 2));
            int n = snb[seg] + nt * 16 + (lane & 15);
            int k = skb[seg] + kt * 32 + slot;
            float v = 0.0f;
            switch (lay) {
                case 0: if (n < 50  && k < 75)  v = W_input[n * 75 + k]; break;
                case 1: if (n < 75  && k < 50)  v = W_h1[n * 50 + k]; break;
                case 2: if (n < 75  && k < 75)  v = W_h2[n * 75 + k] * TANH_SCALE; break;
                case 6: if (n < 125 && k < 50)  v = W_h4[n * 50 + k] * TANH_SCALE; break;
                case 7: if (n < 50  && k < 125) v = W_h5[n * 125 + k]; break;
                case 8: if (n < 3   && k < 50)  v = W_out[n * 50 + k]; break;
            }
            dst[idx] = (short)f2h_bits(v);
        }
        return;
    }

    if (blockIdx.x == 74) {
        for (int i = tid; i < BIAS_TOT; i += NT) {
            if (i >= BD && i < B4) continue;
            float v = 0.0f;
            if (i < B1)        { int o = i - BA;   if (o < 50)  v = b_input[o]; }
            else if (i < B2)   { int o = i - B1;   if (o < 75)  v = b_h1[o]; }
            else if (i < BEF)  { int o = i - B2;   if (o < 75)  v = b_h2[o] * TANH_SCALE; }
            else if (i < BD)   { v = 0.0f; }
            else if (i < B5)   { int o = i - B4;   if (o < 125) v = b_h4[o] * TANH_SCALE; }
            else if (i < BOUT) { int o = i - B5;   if (o < 50)  v = b_h5[o]; }
            else               { int o = i - BOUT; if (o < 3)   v = b_out[o]; }
            ws[i] = v;
        }
        for (int i = tid; i < 2048; i += NT) {
            int j = i & 7, lane = (i >> 3) & 63, nt = i >> 9;
            int n = nt * 16 + (lane & 15);
            int k = (nt >> 1) * 32 + 4 * (lane >> 4) + (j & 3) + 16 * (j >> 2);
            wimg[W_NI + i] = (short)f2h_bits(k == n ? -1.0f : 0.0f);
        }
        return;
    }

    __shared__ __align__(16) float A[17500];
    __shared__ float B[675];
    __shared__ float C[256];
    __shared__ float Dd[256];
    __shared__ float Es[256];
    __shared__ float S[232];

    if (blockIdx.x == 71) {
        // ================= E chain =================
        stage(A, W_e2, 16875, tid);
        for (int i = tid; i < 225; i += NT) { Es[i] = W_e3[i]; C[i] = b_e1[i]; }
        __syncthreads();
        for (int o = tid; o < 675; o += NT) {
            int r = o / 225, c = o % 225;
            float s0 = 0.f, s1 = 0.f, s2 = 0.f;
#pragma unroll
            for (int t = 0; t < 75; t += 3) {
                s0 += Es[r * 75 + t]     * A[t * 225 + c];
                s1 += Es[r * 75 + t + 1] * A[(t + 1) * 225 + c];
                s2 += Es[r * 75 + t + 2] * A[(t + 2) * 225 + c];
            }
            B[o] = s0 + s1 + s2;
        }
        for (int o = tid; o < 75; o += NT) {
            float s0 = 0.f, s1 = 0.f, s2 = 0.f;
#pragma unroll
            for (int t = 0; t < 225; t += 3) {
                s0 += A[o * 225 + t]     * C[t];
                s1 += A[o * 225 + t + 1] * C[t + 1];
                s2 += A[o * 225 + t + 2] * C[t + 2];
            }
            Dd[o] = b_e2[o] + s0 + s1 + s2;
        }
        __syncthreads();
        stage(A, W_e1, 16875, tid);
        __syncthreads();
        for (int o = tid; o < 225; o += NT) {
            int r = o / 75, c = o % 75;
            float s0 = 0.f, s1 = 0.f, s2 = 0.f;
#pragma unroll
            for (int t = 0; t < 225; t += 3) {
                s0 += B[r * 225 + t]     * A[t * 75 + c];
                s1 += B[r * 225 + t + 1] * A[(t + 1) * 75 + c];
                s2 += B[r * 225 + t + 2] * A[(t + 2) * 75 + c];
            }
            S[o] = s0 + s1 + s2;
        }
        for (int o = tid; o < 16; o += NT) {
            float s = 0.0f;
            if (o < 3) {
                s = b_e3[o];
                for (int t = 0; t < 75; t++) s += Es[o * 75 + t] * Dd[t];
            }
            ws[STG_BE + o] = s;
        }
        __syncthreads();
        for (int i = tid; i < 3072; i += NT) {
            int j = i & 7, lane = (i >> 3) & 63, frag = i >> 9, pl = frag & 1, kt = frag >> 1;
            int n = lane & 15;
            int k = kt * 32 + 4 * (lane >> 4) + (j & 3) + 16 * (j >> 2);
            float v = (n < 3 && k < 75) ? S[n * 75 + k] : 0.0f;
            float hi = h2f_bits(f2h_bits(v));
            wimg[W_EF + i] = (short)(pl ? f2h_bits(v - hi) : f2h_bits(v));
        }
    } else if (blockIdx.x == 72) {
        // ================= F chain =================
        stage(A,        W_f2, 7500, tid);
        stage(A + 7500, W_f1, 7500, tid);
        for (int i = tid; i < 150; i += NT) { Es[i] = W_f3[i]; C[i] = b_f1[i]; }
        __syncthreads();
        for (int o = tid; o < 450; o += NT) {
            int r = o / 150, c = o % 150;
            float s0 = 0.f, s1 = 0.f;
#pragma unroll
            for (int t = 0; t < 50; t += 2) {
                s0 += Es[r * 50 + t]     * A[t * 150 + c];
                s1 += Es[r * 50 + t + 1] * A[(t + 1) * 150 + c];
            }
            B[o] = s0 + s1;
        }
        for (int o = tid; o < 50; o += NT) {
            float s0 = 0.f, s1 = 0.f;
#pragma unroll
            for (int t = 0; t < 150; t += 2) {
                s0 += A[o * 150 + t]     * C[t];
                s1 += A[o * 150 + t + 1] * C[t + 1];
            }
            Dd[o] = b_f2[o] + s0 + s1;
        }
        __syncthreads();
        for (int o = tid; o < 150; o += NT) {
            int r = o / 50, c = o % 50;
            float s0 = 0.f, s1 = 0.f;
#pragma unroll
            for (int t = 0; t < 150; t += 2) {
                s0 += B[r * 150 + t]     * A[7500 + t * 50 + c];
                s1 += B[r * 150 + t + 1] * A[7500 + (t + 1) * 50 + c];
            }
            S[o] = s0 + s1;
        }
        for (int o = tid; o < 16; o += NT) {
            float s = 0.0f;
            if (o < 3) {
                s = b_f3[o];
                for (int t = 0; t < 50; t++) s += Es[o * 50 + t] * Dd[t];
            }
            ws[STG_BF + o] = s;
        }
        __syncthreads();
        for (int i = tid; i < 2048; i += NT) {
            int j = i & 7, lane = (i >> 3) & 63, frag = i >> 9, pl = frag & 1, kt = frag >> 1;
            int n = lane & 15;
            int k = kt * 32 + 4 * (lane >> 4) + (j & 3) + 16 * (j >> 2);
            float v = (n < 3 && k < 50) ? S[n * 50 + k] : 0.0f;
            float hi = h2f_bits(f2h_bits(v));
            wimg[W_EF + 3072 + i] = (short)(pl ? f2h_bits(v - hi) : f2h_bits(v));
        }
    } else {
        // ================= D chain =================
        stage(A,         W_d2, 7500, tid);
        stage(A + 7500,  W_d3, 7500, tid);
        stage(A + 15000, W_h3, 2500, tid);
        for (int i = tid; i < 150; i += NT) Es[i] = W_d1[i];
        for (int i = tid; i < 50;  i += NT) C[i] = b_d1[i];
        __syncthreads();
        for (int o = tid; o < 450; o += NT) {
            int r = o / 3, c = o % 3;
            float s0 = 0.f, s1 = 0.f;
#pragma unroll
            for (int t = 0; t < 50; t += 2) {
                s0 += A[r * 50 + t]     * Es[t * 3 + c];
                s1 += A[r * 50 + t + 1] * Es[(t + 1) * 3 + c];
            }
            B[o] = s0 + s1;
        }
        for (int o = tid; o < 150; o += NT) {
            float s0 = 0.f, s1 = 0.f;
#pragma unroll
            for (int t = 0; t < 50; t += 2) {
                s0 += A[o * 50 + t]     * C[t];
                s1 += A[o * 50 + t + 1] * C[t + 1];
            }
            Dd[o] = b_d2[o] + s0 + s1;
        }
        __syncthreads();
        for (int o = tid; o < 150; o += NT) {
            int r = o / 3, c = o % 3;
            float s0 = 0.f, s1 = 0.f;
#pragma unroll
            for (int t = 0; t < 150; t += 2) {
                s0 += A[7500 + r * 150 + t]     * B[t * 3 + c];
                s1 += A[7500 + r * 150 + t + 1] * B[(t + 1) * 3 + c];
            }
            Es[o] = s0 + s1;
        }
        for (int o = tid; o < 50; o += NT) {
            float s0 = 0.f, s1 = 0.f;
#pragma unroll
            for (int t = 0; t < 150; t += 2) {
                s0 += A[7500 + o * 150 + t]     * Dd[t];
                s1 += A[7500 + o * 150 + t + 1] * Dd[t + 1];
            }
            C[o] = b_d3[o] + s0 + s1;
        }
        __syncthreads();
        for (int o = tid; o < 150; o += NT) {
            int r = o / 3, c = o % 3;
            float s0 = 0.f, s1 = 0.f;
#pragma unroll
            for (int t = 0; t < 50; t += 2) {
                s0 += A[15000 + r * 50 + t]     * Es[t * 3 + c];
                s1 += A[15000 + r * 50 + t + 1] * Es[(t + 1) * 3 + c];
            }
            S[o] = s0 + s1;
        }
        for (int o = tid; o < 64; o += NT) {
            float v = 0.0f;
            if (o < 50) {
                float s0 = 0.f, s1 = 0.f;
#pragma unroll
                for (int t = 0; t < 50; t += 2) {
                    s0 += A[15000 + o * 50 + t]     * C[t];
                    s1 += A[15000 + o * 50 + t + 1] * C[t + 1];
                }
                v = b_h3[o] + s0 + s1;
            }
            ws[BD + o] = v;
        }
        __syncthreads();
        for (int i = tid; i < 4096; i += NT) {
            int j = i & 7, lane = (i >> 3) & 63, frag = i >> 9, pl = frag & 1, nt = frag >> 1;
            int n = nt * 16 + (lane & 15);
            int k = 4 * (lane >> 4) + (j & 3) + 16 * (j >> 2);
            float v = (n < 50 && k < 3) ? S[n * 3 + k] : 0.0f;
            float hi = h2f_bits(f2h_bits(v));
            wimg[W_D + i] = (short)(pl ? f2h_bits(v - hi) : f2h_bits(v));
        }
    }
}

// ---------------------------------------------------------------------------
// main kernel helpers
// ---------------------------------------------------------------------------
__device__ __forceinline__ half8 gfragH(const short* __restrict__ wl, int off) {
    return *(const half8*)(wl + off);
}

// Build next-layer B-frag from two C-frags of this lane (sigma k-ordering).
__device__ __forceinline__ half8 packB(f32x4 lo, f32x4 hi) {
    union { unsigned u32[4]; half8 v; } u;
    u.u32[0] = packh2(lo[0], lo[1]);
    u.u32[1] = packh2(lo[2], lo[3]);
    u.u32[2] = packh2(hi[0], hi[1]);
    u.u32[3] = packh2(hi[2], hi[3]);
    return u.v;
}
__device__ __forceinline__ half8 packB1(f32x4 lo) {   // upper 16-neuron half absent
    union { unsigned u32[4]; half8 v; } u;
    u.u32[0] = packh2(lo[0], lo[1]);
    u.u32[1] = packh2(lo[2], lo[3]);
    u.u32[2] = 0u; u.u32[3] = 0u;
    return u.v;
}

__device__ __forceinline__ void st16(unsigned int* p, half8 v) {
    union { half8 h; uint4_ u; } c; c.h = v;
    *(uint4_*)p = c.u;
}
__device__ __forceinline__ half8 ld16(const unsigned int* p) {
    union { half8 h; uint4_ u; } c; c.u = *(const uint4_*)p;
    return c.h;
}

__device__ __forceinline__ f32x4 lrelu4(f32x4 v) {
    v[0] = lrelu(v[0]); v[1] = lrelu(v[1]); v[2] = lrelu(v[2]); v[3] = lrelu(v[3]);
    return v;
}
__device__ __forceinline__ f32x4 tanh4(f32x4 v) {
    v[0] = tanh_fast(v[0]); v[1] = tanh_fast(v[1]);
    v[2] = tanh_fast(v[2]); v[3] = tanh_fast(v[3]);
    return v;
}

// ---------------------------------------------------------------------------
// main fused kernel: 48 pixels/wave at (256,4). Layers A/h1 in mt-pairs;
// h2 fused into EF (x3f groups consumed immediately). x1f parked in LDS;
// xdf parked into freed slots. 3-pt-wide chunk loop (R23). No barriers
// after the prologue.
// ---------------------------------------------------------------------------
__global__ __launch_bounds__(256, 4) void fused_mfma(
    const float* __restrict__ xin,
    const float* __restrict__ ws,
    float* __restrict__ out)
{
    __shared__ float patch[2940];          // 3ch x 5r x 196
    __shared__ int stab[96];
    __shared__ unsigned int x1buf[6144];   // 24KB: [wv][kt*3+pt][lane] 16B slots

    const int tid = threadIdx.x;
    const int wv = tid >> 6;
    const int lane = tid & 63;
    const int qd = lane >> 4;
    const int mcol = lane & 15;
    const short* __restrict__ wl = (const short*)(ws + BIAS_TOT) + lane * 8;

    const int g0 = blockIdx.x * MTILE;
    const int bb = g0 / HW;
    const int p0 = g0 - bb * HW;
    const int yb = p0 / IW;
    const int xblk = p0 - yb * IW;
    const float* __restrict__ xb = xin + bb * 3 * HW;

    unsigned int* xpark = x1buf + wv * 1536 + lane * 4;   // +kt*768 +pt*256

    for (int e = tid; e < 2940; e += 256) {
        int cr = e / 196;
        int i  = e - cr * 196;
        int c  = cr / 5, r = cr - c * 5;
        int ty = yb + r - 2; ty = ty < 0 ? -ty : ty; ty = (766 - ty) < ty ? 766 - ty : ty;
        int tx = xblk - 2 + i; tx = tx < 0 ? -tx : tx; tx = (766 - tx) < tx ? 766 - tx : tx;
        patch[cr * 196 + i] = xb[c * HW + ty * IW + tx];
    }
    if (tid < 96) {
        int v = 0;
        if (tid < 75) {
            int c = tid / 25, rem = tid - 25 * c;
            int rr = rem / 5, ss = rem - 5 * rr;
            v = (c * 5 + rr) * 196 + ss;
        }
        stab[tid] = v;
    }
    __syncthreads();

    // build sw B-fragments from LDS patch (lane&15 = pixel, identity k-order).
    half8 swf[3][3];
    {
        int st[3][8];
#pragma unroll
        for (int kt = 0; kt < 3; kt++)
#pragma unroll
            for (int j = 0; j < 8; j++)
                st[kt][j] = stab[kt * 32 + qd * 8 + j];
#pragma unroll
        for (int pt = 0; pt < 3; pt++) {
            const int xloc = wv * 48 + pt * 16 + mcol;
#pragma unroll
            for (int kt = 0; kt < 3; kt++) {
                union { unsigned u32[4]; half8 v; } u;
#pragma unroll
                for (int jj = 0; jj < 8; jj += 2) {
                    float v0 = patch[st[kt][jj]     + xloc];
                    float v1 = patch[st[kt][jj + 1] + xloc];
                    if (kt == 2) {
                        int qq0 = 64 + qd * 8 + jj;
                        v0 = (qq0     < 75) ? v0 : 0.0f;
                        v1 = (qq0 + 1 < 75) ? v1 : 0.0f;
                    }
                    u.u32[jj >> 1] = packh2(v0, v1);
                }
                swf[kt][pt] = u.v;
            }
        }
    }
    // patch is never written again; x1buf is lane-private -> no second barrier.

    // ===== layer A =====  (50x75 -> mt-pairs {0,1},{2,3}; 3 kt)
    half8 x1f[2][3];
#pragma unroll
    for (int g = 0; g < 2; g++) {
        const short* wlg = wl;
        asm volatile("" : "+v"(wlg));      // fence: no cross-group load hoist
        f32x4 acc[2][3];
#pragma unroll
        for (int m = 0; m < 2; m++) {
            f32x4 b = *(const f32x4*)(ws + BA + (2 * g + m) * 16 + qd * 4);
            acc[m][0] = b; acc[m][1] = b; acc[m][2] = b;
        }
#pragma unroll
        for (int kt = 0; kt < 3; kt++)
#pragma unroll
            for (int m = 0; m < 2; m++) {
                half8 w = gfragH(wlg, W_A0 + kt * 2048 + (2 * g + m) * 512);
#pragma unroll
                for (int pt = 0; pt < 3; pt++)
                    acc[m][pt] = MFMAH(w, swf[kt][pt], acc[m][pt]);
            }
#pragma unroll
        for (int pt = 0; pt < 3; pt++) {
            x1f[g][pt] = packB(acc[0][pt], acc[1][pt]);
            st16(xpark + g * 768 + pt * 256, x1f[g][pt]);   // park for EF/NI
        }
    }

    // ===== h1 =====  (75x50 -> mt-pairs {0,1},{2,3} + tail 4; 2 kt), lrelu
    half8 x2f[3][3];
#pragma unroll
    for (int g = 0; g < 2; g++) {
        const short* wlg = wl;
        asm volatile("" : "+v"(wlg));
        f32x4 acc[2][3];
#pragma unroll
        for (int m = 0; m < 2; m++) {
            f32x4 b = *(const f32x4*)(ws + B1 + (2 * g + m) * 16 + qd * 4);
            acc[m][0] = b; acc[m][1] = b; acc[m][2] = b;
        }
#pragma unroll
        for (int kt = 0; kt < 2; kt++)
#pragma unroll
            for (int m = 0; m < 2; m++) {
                half8 w = gfragH(wlg, W_H1A + kt * 2560 + (2 * g + m) * 512);
#pragma unroll
                for (int pt = 0; pt < 3; pt++)
                    acc[m][pt] = MFMAH(w, x1f[kt][pt], acc[m][pt]);
            }
#pragma unroll
        for (int pt = 0; pt < 3; pt++)
            x2f[g][pt] = packB(lrelu4(acc[0][pt]), lrelu4(acc[1][pt]));
    }
    {   // tail mt=4  (x1f regs die here)
        const short* wlg = wl;
        asm volatile("" : "+v"(wlg));
        f32x4 acc[3];
        {
            f32x4 b = *(const f32x4*)(ws + B1 + 4 * 16 + qd * 4);
            acc[0] = b; acc[1] = b; acc[2] = b;
        }
#pragma unroll
        for (int kt = 0; kt < 2; kt++) {
            half8 w = gfragH(wlg, W_H1A + kt * 2560 + 4 * 512);
#pragma unroll
            for (int pt = 0; pt < 3; pt++)
                acc[pt] = MFMAH(w, x1f[kt][pt], acc[pt]);
        }
#pragma unroll
        for (int pt = 0; pt < 3; pt++)
            x2f[2][pt] = packB1(lrelu4(acc[pt]));
    }

    // ===== h2 fused into EF =====  each x3f group consumed immediately.
    f32x4 accEF[3];
    {
        f32x4 be = *(const f32x4*)(ws + STG_BE + qd * 4);
        f32x4 bf = *(const f32x4*)(ws + STG_BF + qd * 4);
        f32x4 b = be + bf;
        accEF[0] = b; accEF[1] = b; accEF[2] = b;
    }
#pragma unroll
    for (int g = 0; g < 2; g++) {      // h2 mt-pairs {0,1},{2,3} -> E kt=g
        const short* wlg = wl;
        asm volatile("" : "+v"(wlg));
        f32x4 acc[2][3];
#pragma unroll
        for (int m = 0; m < 2; m++) {
            f32x4 b = *(const f32x4*)(ws + B2 + (2 * g + m) * 16 + qd * 4);
            acc[m][0] = b; acc[m][1] = b; acc[m][2] = b;
        }
#pragma unroll
        for (int kt = 0; kt < 3; kt++)
#pragma unroll
            for (int m = 0; m < 2; m++) {
                half8 w = gfragH(wlg, W_H2A + kt * 2560 + (2 * g + m) * 512);
#pragma unroll
                for (int pt = 0; pt < 3; pt++)
                    acc[m][pt] = MFMAH(w, x2f[kt][pt], acc[m][pt]);
            }
        half8 wh = gfragH(wlg, W_EF + g * 1024);
        half8 wo = gfragH(wlg, W_EF + g * 1024 + 512);
#pragma unroll
        for (int pt = 0; pt < 3; pt++) {
            half8 t = packB(tanh4(acc[0][pt]), tanh4(acc[1][pt]));
            accEF[pt] = MFMAH(wh, t, accEF[pt]);
            accEF[pt] = MFMAH(wo, t, accEF[pt]);
        }
    }
    {   // h2 tail mt=4 -> E kt=2  (x2f dies here)
        const short* wlg = wl;
        asm volatile("" : "+v"(wlg));
        f32x4 acc[3];
        {
            f32x4 b = *(const f32x4*)(ws + B2 + 4 * 16 + qd * 4);
            acc[0] = b; acc[1] = b; acc[2] = b;
        }
#pragma unroll
        for (int kt = 0; kt < 3; kt++) {
            half8 w = gfragH(wlg, W_H2A + kt * 2560 + 4 * 512);
#pragma unroll
            for (int pt = 0; pt < 3; pt++)
                acc[pt] = MFMAH(w, x2f[kt][pt], acc[pt]);
        }
        half8 wh = gfragH(wlg, W_EF + 2 * 1024);
        half8 wo = gfragH(wlg, W_EF + 2 * 1024 + 512);
#pragma unroll
        for (int pt = 0; pt < 3; pt++) {
            half8 t = packB1(tanh4(acc[pt]));
            accEF[pt] = MFMAH(wh, t, accEF[pt]);
            accEF[pt] = MFMAH(wo, t, accEF[pt]);
        }
    }
    // unpark x1f for the F part + NI (lane-local ds_read_b128 x6)
    half8 x1r[2][3];
#pragma unroll
    for (int kt = 0; kt < 2; kt++)
#pragma unroll
        for (int pt = 0; pt < 3; pt++)
            x1r[kt][pt] = ld16(xpark + kt * 768 + pt * 256);
#pragma unroll
    for (int kt = 0; kt < 2; kt++) {   // F part
        half8 wh = gfragH(wl, W_EF + 3072 + kt * 1024);
        half8 wo = gfragH(wl, W_EF + 3072 + kt * 1024 + 512);
#pragma unroll
        for (int pt = 0; pt < 3; pt++) {
            accEF[pt] = MFMAH(wh, x1r[kt][pt], accEF[pt]);
            accEF[pt] = MFMAH(wo, x1r[kt][pt], accEF[pt]);
        }
    }
    half8 x4f[3];
#pragma unroll
    for (int pt = 0; pt < 3; pt++)
        x4f[pt] = packB1(lrelu4(accEF[pt]));

    // ===== NI first: x6a init = b5 - x1 (x1r's LAST use; frees park slots)
    f32x4 x6a[4][3];
#pragma unroll
    for (int mt = 0; mt < 4; mt++) {
        f32x4 b = *(const f32x4*)(ws + B5 + mt * 16 + qd * 4);
        half8 nI = gfragH(wl, W_NI + mt * 512);
#pragma unroll
        for (int pt = 0; pt < 3; pt++)
            x6a[mt][pt] = MFMAH(nI, x1r[mt >> 1][pt], b);
    }

    // ===== D =====  two mt-halves; park xdf into the freed x1 slots
#pragma unroll
    for (int h = 0; h < 2; h++) {
        f32x4 accD[2][3];
#pragma unroll
        for (int m2 = 0; m2 < 2; m2++) {
            f32x4 b = *(const f32x4*)(ws + BD + (h * 2 + m2) * 16 + qd * 4);
            accD[m2][0] = b; accD[m2][1] = b; accD[m2][2] = b;
        }
#pragma unroll
        for (int m2 = 0; m2 < 2; m2++) {
            int mt = h * 2 + m2;
            half8 wh = gfragH(wl, W_D + mt * 1024);
            half8 wo = gfragH(wl, W_D + mt * 1024 + 512);
#pragma unroll
            for (int pt = 0; pt < 3; pt++) {
                accD[m2][pt] = MFMAH(wh, x4f[pt], accD[m2][pt]);
                accD[m2][pt] = MFMAH(wo, x4f[pt], accD[m2][pt]);
            }
        }
#pragma unroll
        for (int pt = 0; pt < 3; pt++)
            st16(xpark + h * 768 + pt * 256, packB(accD[0][pt], accD[1][pt]));
    }

    // ===== h4/h5 chunks: xdf re-read per chunk via opaque pointer =====
#pragma unroll
    for (int c = 0; c < 4; c++) {
        const unsigned int* xr = xpark;
        asm volatile("" : "+v"(xr));   // opaque: block LICM hoist of the reads
        half8 xd[2][3];
#pragma unroll
        for (int kt = 0; kt < 2; kt++)
#pragma unroll
            for (int pt = 0; pt < 3; pt++)
                xd[kt][pt] = ld16(xr + kt * 768 + pt * 256);
        f32x4 acc5[2][3];
#pragma unroll
        for (int mt2 = 0; mt2 < 2; mt2++) {
            f32x4 b = *(const f32x4*)(ws + B4 + c * 32 + mt2 * 16 + qd * 4);
            acc5[mt2][0] = b; acc5[mt2][1] = b; acc5[mt2][2] = b;
        }
#pragma unroll
        for (int kt = 0; kt < 2; kt++)
#pragma unroll
            for (int mt2 = 0; mt2 < 2; mt2++) {
                half8 w = gfragH(wl, W_H4C0 + c * 4096 + (mt2 * 2 + kt) * 512);
#pragma unroll
                for (int pt = 0; pt < 3; pt++)
                    acc5[mt2][pt] = MFMAH(w, xd[kt][pt], acc5[mt2][pt]);
            }
        half8 chf[3];
#pragma unroll
        for (int pt = 0; pt < 3; pt++)
            chf[pt] = packB(tanh4(acc5[0][pt]), tanh4(acc5[1][pt]));
#pragma unroll
        for (int mt = 0; mt < 4; mt++) {
            half8 w = gfragH(wl, W_H5C0 + c * 4096 + mt * 512);
#pragma unroll
            for (int pt = 0; pt < 3; pt++)
                x6a[mt][pt] = MFMAH(w, chf[pt], x6a[mt][pt]);
        }
    }

    // ===== out =====
    f32x4 accO[3];
    {
        f32x4 b = *(const f32x4*)(ws + BOUT + qd * 4);
        accO[0] = b; accO[1] = b; accO[2] = b;
    }
#pragma unroll
    for (int kt = 0; kt < 2; kt++) {
        half8 w = gfragH(wl, W_OUT + kt * 512);
#pragma unroll
        for (int pt = 0; pt < 3; pt++) {
            half8 x6f = packB(x6a[2 * kt][pt], x6a[2 * kt + 1][pt]);
            accO[pt] = MFMAH(w, x6f, accO[pt]);
        }
    }
    // C rows = output channels (0..2 live in qd==0, r<3); cols = pixels.
    if (qd == 0) {
#pragma unroll
        for (int pt = 0; pt < 3; pt++) {
            int p = p0 + wv * 48 + pt * 16 + mcol;
#pragma unroll
            for (int r = 0; r < 3; r++)
                out[(bb * 3 + r) * HW + p] = lrelu(accO[pt][r]);
        }
    }
}

extern "C" void kernel_launch(void* const* d_in, const int* in_sizes, int n_in,
                              void* d_out, int out_size, void* d_ws, size_t ws_size,
                              hipStream_t stream)
{
    const float* xin = (const float*)d_in[0];
    float* ws = (float*)d_ws;

    setup_all<<<75, 256, 0, stream>>>(
        (const float*)d_in[1],  (const float*)d_in[2],   // input
        (const float*)d_in[3],  (const float*)d_in[4],   // h1
        (const float*)d_in[5],  (const float*)d_in[6],   // h2
        (const float*)d_in[7],  (const float*)d_in[8],   // h3
        (const float*)d_in[9],  (const float*)d_in[10],  // h4
        (const float*)d_in[11], (const float*)d_in[12],  // h5
        (const float*)d_in[13], (const float*)d_in[14],  // out
        (const float*)d_in[15], (const float*)d_in[16],  // e1
        (const float*)d_in[17], (const float*)d_in[18],  // e2
        (const float*)d_in[19], (const float*)d_in[20],  // e3
        (const float*)d_in[21], (const float*)d_in[22],  // f1
        (const float*)d_in[23], (const float*)d_in[24],  // f2
        (const float*)d_in[25], (const float*)d_in[26],  // f3
        (const float*)d_in[27], (const float*)d_in[28],  // d1
        (const float*)d_in[29], (const float*)d_in[30],  // d2
        (const float*)d_in[31], (const float*)d_in[32],  // d3
        ws);

    fused_mfma<<<NBLK, 256, 0, stream>>>(xin, ws, (float*)d_out);
}

// Round 12
// 203.786 us; speedup vs baseline: 1.1184x; 1.0736x over previous
//
#include <hip/hip_runtime.h>

// ---------------------------------------------------------------------------
// Round 27 = Round 26 (91.6us) + three contained VALU cuts, structure frozen:
//  1. Prologue: tx reflect computed ONCE per thread (tids<196), ty once per
//     5 rows, 15 unrolled coalesced row loads. ~-150 VALU ops/thread vs the
//     per-element divide/reflect chain.
//  2. swf kt=2 clamp removed: W_A2 columns k>=75 are zero in the weight
//     image and the out-of-range patch reads are finite -> product is 0.
//  3. lrelu for x2f/x4f done packed-f16 AFTER cvt_pkrtz (v_pk_mul_f16 +
//     v_pk_max_f16) instead of f32 before: ~-70 ops. tanh paths untouched.
//  No control-flow/fence/tile changes (R25 lesson: keep passing structure).
// ---------------------------------------------------------------------------

#define IW 384
#define HW (384 * 384)           // 147456
#define NPIX (4 * HW)            // 589824
#define MTILE 192
#define NBLK (NPIX / MTILE)      // 3072

#define TANH_SCALE 2.8853900817779268f   // 2*log2(e), baked into h2/h4 weights

typedef _Float16 half8 __attribute__((ext_vector_type(8)));
typedef _Float16 h2v __attribute__((ext_vector_type(2)));
typedef __fp16 fp16x2 __attribute__((ext_vector_type(2)));
typedef __attribute__((ext_vector_type(4))) float f32x4;
typedef __attribute__((ext_vector_type(4))) unsigned int uint4_;

#define MFMAH(A, B, C) __builtin_amdgcn_mfma_f32_16x16x32_f16((A), (B), (C), 0, 0, 0)

// bias table offsets (dwords in ws)
#define BA   0
#define B1   64
#define B2   144
#define BEF  224
#define BD   240
#define B4   304
#define B5   432
#define BOUT 496
#define BIAS_TOT 512

// weight image segment offsets (shorts, after bias table). frag = 512 shorts.
#define W_A0   0
#define W_A1   2048
#define W_A2   4096
#define W_H1A  6144
#define W_H1B  8704
#define W_H2A  11264
#define W_H2B  13824
#define W_H2C  16384
#define W_EF   18944    // E: 6 frags hi/lo (kt-major), F: 4 frags at +3072
#define W_D    24064    // 8 frags hi/lo (nt-major)
#define W_H4C0 28160    // chunk c: h4 at 28160+c*4096
#define W_H5C0 30208    //          h5 at 30208+c*4096
#define W_OUT  44544
#define W_NI   45568    // negated identity: 4 frags (nt, kt=nt>>1 baked)
#define W_TOT  47616

// be / bf slots (dword offsets, after images): 16 entries each, zero-padded
#define STG_BE  24320
#define STG_BF  24336

__device__ __forceinline__ float lrelu(float v) { return fmaxf(v, 0.01f * v); }

#if __has_builtin(__builtin_amdgcn_exp2f)
#define EXP2F __builtin_amdgcn_exp2f
#else
#define EXP2F __builtin_exp2f
#endif

// input pre-scaled by 2*log2(e) (baked into weights): tanh = 1 - 2/(2^v + 1)
__device__ __forceinline__ float tanh_fast(float v) {
    float e = EXP2F(v);
    return __builtin_fmaf(-2.0f, __builtin_amdgcn_rcpf(e + 1.0f), 1.0f);
}

__device__ __forceinline__ unsigned short f2h_bits(float v) {
    union { _Float16 h; unsigned short s; } u; u.h = (_Float16)v; return u.s;
}
__device__ __forceinline__ float h2f_bits(unsigned short s) {
    union { _Float16 h; unsigned short s; } u; u.s = s; return (float)u.h;
}
__device__ __forceinline__ unsigned packh2(float a, float b) {
    union { fp16x2 h; unsigned u; } u;
    u.h = __builtin_amdgcn_cvt_pkrtz(a, b);
    return u.u;
}

// packed-f16 leaky relu on 2 halves: v_pk_mul_f16 + v_pk_max_f16
__device__ __forceinline__ unsigned lrelu_pkh(unsigned x) {
    union { unsigned u; h2v h; } a, b, r;
    a.u = x;
    b.h = a.h * (h2v)((_Float16)0.01f);
    r.h = __builtin_elementwise_max(a.h, b.h);
    return r.u;
}

// deep-pipelined global->LDS staging: float4 x unroll-4
__device__ __forceinline__ void stage(float* dst, const float* __restrict__ src,
                                      int n, int tid) {
    int n4 = n >> 2;
    float4* d = (float4*)dst;
    const float4* s = (const float4*)src;
#pragma unroll 4
    for (int i = tid; i < n4; i += 256) d[i] = s[i];
    for (int i = (n4 << 2) + tid; i < n; i += 256) dst[i] = src[i];
}

// ---------------------------------------------------------------------------
// setup_all: 75 independent blocks x 256 threads. (identical to R26)
// ---------------------------------------------------------------------------
__global__ __launch_bounds__(256) void setup_all(
    const float* __restrict__ W_input, const float* __restrict__ b_input,
    const float* __restrict__ W_h1,  const float* __restrict__ b_h1,
    const float* __restrict__ W_h2,  const float* __restrict__ b_h2,
    const float* __restrict__ W_h3,  const float* __restrict__ b_h3,
    const float* __restrict__ W_h4,  const float* __restrict__ b_h4,
    const float* __restrict__ W_h5,  const float* __restrict__ b_h5,
    const float* __restrict__ W_out, const float* __restrict__ b_out,
    const float* __restrict__ W_e1,  const float* __restrict__ b_e1,
    const float* __restrict__ W_e2,  const float* __restrict__ b_e2,
    const float* __restrict__ W_e3,  const float* __restrict__ b_e3,
    const float* __restrict__ W_f1,  const float* __restrict__ b_f1,
    const float* __restrict__ W_f2,  const float* __restrict__ b_f2,
    const float* __restrict__ W_f3,  const float* __restrict__ b_f3,
    const float* __restrict__ W_d1,  const float* __restrict__ b_d1,
    const float* __restrict__ W_d2,  const float* __restrict__ b_d2,
    const float* __restrict__ W_d3,  const float* __restrict__ b_d3,
    float* __restrict__ ws)
{
    const int tid = threadIdx.x;
    const int NT = 256;
    short* wimg = (short*)(ws + BIAS_TOT);

    if (blockIdx.x < 71) {
        const int soff[17] = {W_A0,W_A1,W_A2, W_H1A,W_H1B, W_H2A,W_H2B,W_H2C,
                              W_H4C0,W_H5C0, W_H4C0+4096,W_H5C0+4096,
                              W_H4C0+8192,W_H5C0+8192, W_H4C0+12288,W_H5C0+12288,
                              W_OUT};
        const int slay[17] = {0,0,0, 1,1, 2,2,2, 6,7, 6,7, 6,7, 6,7, 8};
        const int sNT[17]  = {4,4,4, 5,5, 5,5,5, 2,4, 2,4, 2,4, 2,4, 1};
        const int sKTS[17] = {1,1,1, 1,1, 1,1,1, 2,1, 2,1, 2,1, 2,1, 2};
        const int snb[17]  = {0,0,0, 0,0, 0,0,0, 0,0, 32,0, 64,0, 96,0, 0};
        const int skb[17]  = {0,32,64, 0,32, 0,32,64, 0,0, 0,32, 0,64, 0,96, 0};

        int seg = 0, local = blockIdx.x;
        while (seg < 16 && local >= sNT[seg] * sKTS[seg]) { local -= sNT[seg] * sKTS[seg]; seg++; }
        const int kts = sKTS[seg];
        const int kt = local % kts, nt = local / kts;
        const int lay = slay[seg];
        short* dst = wimg + soff[seg] + local * 512;

#pragma unroll
        for (int t = 0; t < 2; t++) {
            int idx = tid + t * 256;
            int j = idx & 7, lane = idx >> 3;
            // sigma slot for layers consumed from MFMA C-frags; identity for A.
            int slot = (lay == 0) ? ((lane >> 4) * 8 + j)
                                  : (4 * (lane >> 4) + (j & 3) + 16 * (j >> 2));
            int n = snb[seg] + nt * 16 + (lane & 15);
            int k = skb[seg] + kt * 32 + slot;
            float v = 0.0f;
            switch (lay) {
                case 0: if (n < 50  && k < 75)  v = W_input[n * 75 + k]; break;
                case 1: if (n < 75  && k < 50)  v = W_h1[n * 50 + k]; break;
                case 2: if (n < 75  && k < 75)  v = W_h2[n * 75 + k] * TANH_SCALE; break;
                case 6: if (n < 125 && k < 50)  v = W_h4[n * 50 + k] * TANH_SCALE; break;
                case 7: if (n < 50  && k < 125) v = W_h5[n * 125 + k]; break;
                case 8: if (n < 3   && k < 50)  v = W_out[n * 50 + k]; break;
            }
            dst[idx] = (short)f2h_bits(v);
        }
        return;
    }

    if (blockIdx.x == 74) {
        for (int i = tid; i < BIAS_TOT; i += NT) {
            if (i >= BD && i < B4) continue;
            float v = 0.0f;
            if (i < B1)        { int o = i - BA;   if (o < 50)  v = b_input[o]; }
            else if (i < B2)   { int o = i - B1;   if (o < 75)  v = b_h1[o]; }
            else if (i < BEF)  { int o = i - B2;   if (o < 75)  v = b_h2[o] * TANH_SCALE; }
            else if (i < BD)   { v = 0.0f; }
            else if (i < B5)   { int o = i - B4;   if (o < 125) v = b_h4[o] * TANH_SCALE; }
            else if (i < BOUT) { int o = i - B5;   if (o < 50)  v = b_h5[o]; }
            else               { int o = i - BOUT; if (o < 3)   v = b_out[o]; }
            ws[i] = v;
        }
        for (int i = tid; i < 2048; i += NT) {
            int j = i & 7, lane = (i >> 3) & 63, nt = i >> 9;
            int n = nt * 16 + (lane & 15);
            int k = (nt >> 1) * 32 + 4 * (lane >> 4) + (j & 3) + 16 * (j >> 2);
            wimg[W_NI + i] = (short)f2h_bits(k == n ? -1.0f : 0.0f);
        }
        return;
    }

    __shared__ __align__(16) float A[17500];
    __shared__ float B[675];
    __shared__ float C[256];
    __shared__ float Dd[256];
    __shared__ float Es[256];
    __shared__ float S[232];

    if (blockIdx.x == 71) {
        // ================= E chain =================
        stage(A, W_e2, 16875, tid);
        for (int i = tid; i < 225; i += NT) { Es[i] = W_e3[i]; C[i] = b_e1[i]; }
        __syncthreads();
        for (int o = tid; o < 675; o += NT) {
            int r = o / 225, c = o % 225;
            float s0 = 0.f, s1 = 0.f, s2 = 0.f;
#pragma unroll
            for (int t = 0; t < 75; t += 3) {
                s0 += Es[r * 75 + t]     * A[t * 225 + c];
                s1 += Es[r * 75 + t + 1] * A[(t + 1) * 225 + c];
                s2 += Es[r * 75 + t + 2] * A[(t + 2) * 225 + c];
            }
            B[o] = s0 + s1 + s2;
        }
        for (int o = tid; o < 75; o += NT) {
            float s0 = 0.f, s1 = 0.f, s2 = 0.f;
#pragma unroll
            for (int t = 0; t < 225; t += 3) {
                s0 += A[o * 225 + t]     * C[t];
                s1 += A[o * 225 + t + 1] * C[t + 1];
                s2 += A[o * 225 + t + 2] * C[t + 2];
            }
            Dd[o] = b_e2[o] + s0 + s1 + s2;
        }
        __syncthreads();
        stage(A, W_e1, 16875, tid);
        __syncthreads();
        for (int o = tid; o < 225; o += NT) {
            int r = o / 75, c = o % 75;
            float s0 = 0.f, s1 = 0.f, s2 = 0.f;
#pragma unroll
            for (int t = 0; t < 225; t += 3) {
                s0 += B[r * 225 + t]     * A[t * 75 + c];
                s1 += B[r * 225 + t + 1] * A[(t + 1) * 75 + c];
                s2 += B[r * 225 + t + 2] * A[(t + 2) * 75 + c];
            }
            S[o] = s0 + s1 + s2;
        }
        for (int o = tid; o < 16; o += NT) {
            float s = 0.0f;
            if (o < 3) {
                s = b_e3[o];
                for (int t = 0; t < 75; t++) s += Es[o * 75 + t] * Dd[t];
            }
            ws[STG_BE + o] = s;
        }
        __syncthreads();
        for (int i = tid; i < 3072; i += NT) {
            int j = i & 7, lane = (i >> 3) & 63, frag = i >> 9, pl = frag & 1, kt = frag >> 1;
            int n = lane & 15;
            int k = kt * 32 + 4 * (lane >> 4) + (j & 3) + 16 * (j >> 2);
            float v = (n < 3 && k < 75) ? S[n * 75 + k] : 0.0f;
            float hi = h2f_bits(f2h_bits(v));
            wimg[W_EF + i] = (short)(pl ? f2h_bits(v - hi) : f2h_bits(v));
        }
    } else if (blockIdx.x == 72) {
        // ================= F chain =================
        stage(A,        W_f2, 7500, tid);
        stage(A + 7500, W_f1, 7500, tid);
        for (int i = tid; i < 150; i += NT) { Es[i] = W_f3[i]; C[i] = b_f1[i]; }
        __syncthreads();
        for (int o = tid; o < 450; o += NT) {
            int r = o / 150, c = o % 150;
            float s0 = 0.f, s1 = 0.f;
#pragma unroll
            for (int t = 0; t < 50; t += 2) {
                s0 += Es[r * 50 + t]     * A[t * 150 + c];
                s1 += Es[r * 50 + t + 1] * A[(t + 1) * 150 + c];
            }
            B[o] = s0 + s1;
        }
        for (int o = tid; o < 50; o += NT) {
            float s0 = 0.f, s1 = 0.f;
#pragma unroll
            for (int t = 0; t < 150; t += 2) {
                s0 += A[o * 150 + t]     * C[t];
                s1 += A[o * 150 + t + 1] * C[t + 1];
            }
            Dd[o] = b_f2[o] + s0 + s1;
        }
        __syncthreads();
        for (int o = tid; o < 150; o += NT) {
            int r = o / 50, c = o % 50;
            float s0 = 0.f, s1 = 0.f;
#pragma unroll
            for (int t = 0; t < 150; t += 2) {
                s0 += B[r * 150 + t]     * A[7500 + t * 50 + c];
                s1 += B[r * 150 + t + 1] * A[7500 + (t + 1) * 50 + c];
            }
            S[o] = s0 + s1;
        }
        for (int o = tid; o < 16; o += NT) {
            float s = 0.0f;
            if (o < 3) {
                s = b_f3[o];
                for (int t = 0; t < 50; t++) s += Es[o * 50 + t] * Dd[t];
            }
            ws[STG_BF + o] = s;
        }
        __syncthreads();
        for (int i = tid; i < 2048; i += NT) {
            int j = i & 7, lane = (i >> 3) & 63, frag = i >> 9, pl = frag & 1, kt = frag >> 1;
            int n = lane & 15;
            int k = kt * 32 + 4 * (lane >> 4) + (j & 3) + 16 * (j >> 2);
            float v = (n < 3 && k < 50) ? S[n * 50 + k] : 0.0f;
            float hi = h2f_bits(f2h_bits(v));
            wimg[W_EF + 3072 + i] = (short)(pl ? f2h_bits(v - hi) : f2h_bits(v));
        }
    } else {
        // ================= D chain =================
        stage(A,         W_d2, 7500, tid);
        stage(A + 7500,  W_d3, 7500, tid);
        stage(A + 15000, W_h3, 2500, tid);
        for (int i = tid; i < 150; i += NT) Es[i] = W_d1[i];
        for (int i = tid; i < 50;  i += NT) C[i] = b_d1[i];
        __syncthreads();
        for (int o = tid; o < 450; o += NT) {
            int r = o / 3, c = o % 3;
            float s0 = 0.f, s1 = 0.f;
#pragma unroll
            for (int t = 0; t < 50; t += 2) {
                s0 += A[r * 50 + t]     * Es[t * 3 + c];
                s1 += A[r * 50 + t + 1] * Es[(t + 1) * 3 + c];
            }
            B[o] = s0 + s1;
        }
        for (int o = tid; o < 150; o += NT) {
            float s0 = 0.f, s1 = 0.f;
#pragma unroll
            for (int t = 0; t < 50; t += 2) {
                s0 += A[o * 50 + t]     * C[t];
                s1 += A[o * 50 + t + 1] * C[t + 1];
            }
            Dd[o] = b_d2[o] + s0 + s1;
        }
        __syncthreads();
        for (int o = tid; o < 150; o += NT) {
            int r = o / 3, c = o % 3;
            float s0 = 0.f, s1 = 0.f;
#pragma unroll
            for (int t = 0; t < 150; t += 2) {
                s0 += A[7500 + r * 150 + t]     * B[t * 3 + c];
                s1 += A[7500 + r * 150 + t + 1] * B[(t + 1) * 3 + c];
            }
            Es[o] = s0 + s1;
        }
        for (int o = tid; o < 50; o += NT) {
            float s0 = 0.f, s1 = 0.f;
#pragma unroll
            for (int t = 0; t < 150; t += 2) {
                s0 += A[7500 + o * 150 + t]     * Dd[t];
                s1 += A[7500 + o * 150 + t + 1] * Dd[t + 1];
            }
            C[o] = b_d3[o] + s0 + s1;
        }
        __syncthreads();
        for (int o = tid; o < 150; o += NT) {
            int r = o / 3, c = o % 3;
            float s0 = 0.f, s1 = 0.f;
#pragma unroll
            for (int t = 0; t < 50; t += 2) {
                s0 += A[15000 + r * 50 + t]     * Es[t * 3 + c];
                s1 += A[15000 + r * 50 + t + 1] * Es[(t + 1) * 3 + c];
            }
            S[o] = s0 + s1;
        }
        for (int o = tid; o < 64; o += NT) {
            float v = 0.0f;
            if (o < 50) {
                float s0 = 0.f, s1 = 0.f;
#pragma unroll
                for (int t = 0; t < 50; t += 2) {
                    s0 += A[15000 + o * 50 + t]     * C[t];
                    s1 += A[15000 + o * 50 + t + 1] * C[t + 1];
                }
                v = b_h3[o] + s0 + s1;
            }
            ws[BD + o] = v;
        }
        __syncthreads();
        for (int i = tid; i < 4096; i += NT) {
            int j = i & 7, lane = (i >> 3) & 63, frag = i >> 9, pl = frag & 1, nt = frag >> 1;
            int n = nt * 16 + (lane & 15);
            int k = 4 * (lane >> 4) + (j & 3) + 16 * (j >> 2);
            float v = (n < 50 && k < 3) ? S[n * 3 + k] : 0.0f;
            float hi = h2f_bits(f2h_bits(v));
            wimg[W_D + i] = (short)(pl ? f2h_bits(v - hi) : f2h_bits(v));
        }
    }
}

// ---------------------------------------------------------------------------
// main kernel helpers
// ---------------------------------------------------------------------------
__device__ __forceinline__ half8 gfragH(const short* __restrict__ wl, int off) {
    return *(const half8*)(wl + off);
}

// Build next-layer B-frag from two C-frags of this lane (sigma k-ordering).
__device__ __forceinline__ half8 packB(f32x4 lo, f32x4 hi) {
    union { unsigned u32[4]; half8 v; } u;
    u.u32[0] = packh2(lo[0], lo[1]);
    u.u32[1] = packh2(lo[2], lo[3]);
    u.u32[2] = packh2(hi[0], hi[1]);
    u.u32[3] = packh2(hi[2], hi[3]);
    return u.v;
}
__device__ __forceinline__ half8 packB1(f32x4 lo) {   // upper 16-neuron half absent
    union { unsigned u32[4]; half8 v; } u;
    u.u32[0] = packh2(lo[0], lo[1]);
    u.u32[1] = packh2(lo[2], lo[3]);
    u.u32[2] = 0u; u.u32[3] = 0u;
    return u.v;
}
// packB with packed-f16 lrelu applied after the pack
__device__ __forceinline__ half8 packB_lr(f32x4 lo, f32x4 hi) {
    union { unsigned u32[4]; half8 v; } u;
    u.u32[0] = lrelu_pkh(packh2(lo[0], lo[1]));
    u.u32[1] = lrelu_pkh(packh2(lo[2], lo[3]));
    u.u32[2] = lrelu_pkh(packh2(hi[0], hi[1]));
    u.u32[3] = lrelu_pkh(packh2(hi[2], hi[3]));
    return u.v;
}
__device__ __forceinline__ half8 packB1_lr(f32x4 lo) {
    union { unsigned u32[4]; half8 v; } u;
    u.u32[0] = lrelu_pkh(packh2(lo[0], lo[1]));
    u.u32[1] = lrelu_pkh(packh2(lo[2], lo[3]));
    u.u32[2] = 0u; u.u32[3] = 0u;
    return u.v;
}

__device__ __forceinline__ void st16(unsigned int* p, half8 v) {
    union { half8 h; uint4_ u; } c; c.h = v;
    *(uint4_*)p = c.u;
}
__device__ __forceinline__ half8 ld16(const unsigned int* p) {
    union { half8 h; uint4_ u; } c; c.u = *(const uint4_*)p;
    return c.h;
}

__device__ __forceinline__ f32x4 lrelu4(f32x4 v) {
    v[0] = lrelu(v[0]); v[1] = lrelu(v[1]); v[2] = lrelu(v[2]); v[3] = lrelu(v[3]);
    return v;
}
__device__ __forceinline__ f32x4 tanh4(f32x4 v) {
    v[0] = tanh_fast(v[0]); v[1] = tanh_fast(v[1]);
    v[2] = tanh_fast(v[2]); v[3] = tanh_fast(v[3]);
    return v;
}

// ---------------------------------------------------------------------------
// main fused kernel: 48 pixels/wave at (256,4). Layers A/h1 in mt-pairs;
// h2 fused into EF; 3-pt-wide chunk loop. x1f parked in LDS; xdf parked into
// freed slots. No barriers after the prologue.
// ---------------------------------------------------------------------------
__global__ __launch_bounds__(256, 4) void fused_mfma(
    const float* __restrict__ xin,
    const float* __restrict__ ws,
    float* __restrict__ out)
{
    __shared__ float patch[2940];          // 3ch x 5r x 196
    __shared__ int stab[96];
    __shared__ unsigned int x1buf[6144];   // 24KB: [wv][kt*3+pt][lane] 16B slots

    const int tid = threadIdx.x;
    const int wv = tid >> 6;
    const int lane = tid & 63;
    const int qd = lane >> 4;
    const int mcol = lane & 15;
    const short* __restrict__ wl = (const short*)(ws + BIAS_TOT) + lane * 8;

    const int g0 = blockIdx.x * MTILE;
    const int bb = g0 / HW;
    const int p0 = g0 - bb * HW;
    const int yb = p0 / IW;
    const int xblk = p0 - yb * IW;
    const float* __restrict__ xb = xin + bb * 3 * HW;

    unsigned int* xpark = x1buf + wv * 1536 + lane * 4;   // +kt*768 +pt*256

    // prologue: tx reflect once per thread; 15 unrolled coalesced row loads
    {
        int tyr[5];
#pragma unroll
        for (int r = 0; r < 5; r++) {
            int ty = yb + r - 2; ty = ty < 0 ? -ty : ty; ty = (766 - ty) < ty ? 766 - ty : ty;
            tyr[r] = ty * IW;
        }
        if (tid < 196) {
            int tx = xblk - 2 + tid; tx = tx < 0 ? -tx : tx; tx = (766 - tx) < tx ? 766 - tx : tx;
#pragma unroll
            for (int cr = 0; cr < 15; cr++) {
                const int c = cr / 5, r = cr % 5;
                patch[cr * 196 + tid] = xb[c * HW + tyr[r] + tx];
            }
        }
    }
    if (tid < 96) {
        int v = 0;
        if (tid < 75) {
            int c = tid / 25, rem = tid - 25 * c;
            int rr = rem / 5, ss = rem - 5 * rr;
            v = (c * 5 + rr) * 196 + ss;
        }
        stab[tid] = v;
    }
    __syncthreads();

    // build sw B-fragments from LDS patch (lane&15 = pixel, identity k-order).
    // k>=75 garbage in kt=2 is finite and killed by zero-padded W_A2 columns.
    half8 swf[3][3];
    {
        int st[3][8];
#pragma unroll
        for (int kt = 0; kt < 3; kt++)
#pragma unroll
            for (int j = 0; j < 8; j++)
                st[kt][j] = stab[kt * 32 + qd * 8 + j];
#pragma unroll
        for (int pt = 0; pt < 3; pt++) {
            const int xloc = wv * 48 + pt * 16 + mcol;
#pragma unroll
            for (int kt = 0; kt < 3; kt++) {
                union { unsigned u32[4]; half8 v; } u;
#pragma unroll
                for (int jj = 0; jj < 8; jj += 2) {
                    float v0 = patch[st[kt][jj]     + xloc];
                    float v1 = patch[st[kt][jj + 1] + xloc];
                    u.u32[jj >> 1] = packh2(v0, v1);
                }
                swf[kt][pt] = u.v;
            }
        }
    }
    // patch is never written again; x1buf is lane-private -> no second barrier.

    // ===== layer A =====  (50x75 -> mt-pairs {0,1},{2,3}; 3 kt)
    half8 x1f[2][3];
#pragma unroll
    for (int g = 0; g < 2; g++) {
        const short* wlg = wl;
        asm volatile("" : "+v"(wlg));      // fence: no cross-group load hoist
        f32x4 acc[2][3];
#pragma unroll
        for (int m = 0; m < 2; m++) {
            f32x4 b = *(const f32x4*)(ws + BA + (2 * g + m) * 16 + qd * 4);
            acc[m][0] = b; acc[m][1] = b; acc[m][2] = b;
        }
#pragma unroll
        for (int kt = 0; kt < 3; kt++)
#pragma unroll
            for (int m = 0; m < 2; m++) {
                half8 w = gfragH(wlg, W_A0 + kt * 2048 + (2 * g + m) * 512);
#pragma unroll
                for (int pt = 0; pt < 3; pt++)
                    acc[m][pt] = MFMAH(w, swf[kt][pt], acc[m][pt]);
            }
#pragma unroll
        for (int pt = 0; pt < 3; pt++) {
            x1f[g][pt] = packB(acc[0][pt], acc[1][pt]);
            st16(xpark + g * 768 + pt * 256, x1f[g][pt]);   // park for EF/NI
        }
    }

    // ===== h1 =====  (75x50 -> mt-pairs {0,1},{2,3} + tail 4; 2 kt), lrelu
    half8 x2f[3][3];
#pragma unroll
    for (int g = 0; g < 2; g++) {
        const short* wlg = wl;
        asm volatile("" : "+v"(wlg));
        f32x4 acc[2][3];
#pragma unroll
        for (int m = 0; m < 2; m++) {
            f32x4 b = *(const f32x4*)(ws + B1 + (2 * g + m) * 16 + qd * 4);
            acc[m][0] = b; acc[m][1] = b; acc[m][2] = b;
        }
#pragma unroll
        for (int kt = 0; kt < 2; kt++)
#pragma unroll
            for (int m = 0; m < 2; m++) {
                half8 w = gfragH(wlg, W_H1A + kt * 2560 + (2 * g + m) * 512);
#pragma unroll
                for (int pt = 0; pt < 3; pt++)
                    acc[m][pt] = MFMAH(w, x1f[kt][pt], acc[m][pt]);
            }
#pragma unroll
        for (int pt = 0; pt < 3; pt++)
            x2f[g][pt] = packB_lr(acc[0][pt], acc[1][pt]);
    }
    {   // tail mt=4  (x1f regs die here)
        const short* wlg = wl;
        asm volatile("" : "+v"(wlg));
        f32x4 acc[3];
        {
            f32x4 b = *(const f32x4*)(ws + B1 + 4 * 16 + qd * 4);
            acc[0] = b; acc[1] = b; acc[2] = b;
        }
#pragma unroll
        for (int kt = 0; kt < 2; kt++) {
            half8 w = gfragH(wlg, W_H1A + kt * 2560 + 4 * 512);
#pragma unroll
            for (int pt = 0; pt < 3; pt++)
                acc[pt] = MFMAH(w, x1f[kt][pt], acc[pt]);
        }
#pragma unroll
        for (int pt = 0; pt < 3; pt++)
            x2f[2][pt] = packB1_lr(acc[pt]);
    }

    // ===== h2 fused into EF =====  each x3f group consumed immediately.
    f32x4 accEF[3];
    {
        f32x4 be = *(const f32x4*)(ws + STG_BE + qd * 4);
        f32x4 bf = *(const f32x4*)(ws + STG_BF + qd * 4);
        f32x4 b = be + bf;
        accEF[0] = b; accEF[1] = b; accEF[2] = b;
    }
#pragma unroll
    for (int g = 0; g < 2; g++) {      // h2 mt-pairs {0,1},{2,3} -> E kt=g
        const short* wlg = wl;
        asm volatile("" : "+v"(wlg));
        f32x4 acc[2][3];
#pragma unroll
        for (int m = 0; m < 2; m++) {
            f32x4 b = *(const f32x4*)(ws + B2 + (2 * g + m) * 16 + qd * 4);
            acc[m][0] = b; acc[m][1] = b; acc[m][2] = b;
        }
#pragma unroll
        for (int kt = 0; kt < 3; kt++)
#pragma unroll
            for (int m = 0; m < 2; m++) {
                half8 w = gfragH(wlg, W_H2A + kt * 2560 + (2 * g + m) * 512);
#pragma unroll
                for (int pt = 0; pt < 3; pt++)
                    acc[m][pt] = MFMAH(w, x2f[kt][pt], acc[m][pt]);
            }
        half8 wh = gfragH(wlg, W_EF + g * 1024);
        half8 wo = gfragH(wlg, W_EF + g * 1024 + 512);
#pragma unroll
        for (int pt = 0; pt < 3; pt++) {
            half8 t = packB(tanh4(acc[0][pt]), tanh4(acc[1][pt]));
            accEF[pt] = MFMAH(wh, t, accEF[pt]);
            accEF[pt] = MFMAH(wo, t, accEF[pt]);
        }
    }
    {   // h2 tail mt=4 -> E kt=2  (x2f dies here)
        const short* wlg = wl;
        asm volatile("" : "+v"(wlg));
        f32x4 acc[3];
        {
            f32x4 b = *(const f32x4*)(ws + B2 + 4 * 16 + qd * 4);
            acc[0] = b; acc[1] = b; acc[2] = b;
        }
#pragma unroll
        for (int kt = 0; kt < 3; kt++) {
            half8 w = gfragH(wlg, W_H2A + kt * 2560 + 4 * 512);
#pragma unroll
            for (int pt = 0; pt < 3; pt++)
                acc[pt] = MFMAH(w, x2f[kt][pt], acc[pt]);
        }
        half8 wh = gfragH(wlg, W_EF + 2 * 1024);
        half8 wo = gfragH(wlg, W_EF + 2 * 1024 + 512);
#pragma unroll
        for (int pt = 0; pt < 3; pt++) {
            half8 t = packB1(tanh4(acc[pt]));
            accEF[pt] = MFMAH(wh, t, accEF[pt]);
            accEF[pt] = MFMAH(wo, t, accEF[pt]);
        }
    }
    // unpark x1f for the F part + NI (lane-local ds_read_b128 x6)
    half8 x1r[2][3];
#pragma unroll
    for (int kt = 0; kt < 2; kt++)
#pragma unroll
        for (int pt = 0; pt < 3; pt++)
            x1r[kt][pt] = ld16(xpark + kt * 768 + pt * 256);
#pragma unroll
    for (int kt = 0; kt < 2; kt++) {   // F part
        half8 wh = gfragH(wl, W_EF + 3072 + kt * 1024);
        half8 wo = gfragH(wl, W_EF + 3072 + kt * 1024 + 512);
#pragma unroll
        for (int pt = 0; pt < 3; pt++) {
            accEF[pt] = MFMAH(wh, x1r[kt][pt], accEF[pt]);
            accEF[pt] = MFMAH(wo, x1r[kt][pt], accEF[pt]);
        }
    }
    half8 x4f[3];
#pragma unroll
    for (int pt = 0; pt < 3; pt++)
        x4f[pt] = packB1_lr(accEF[pt]);

    // ===== NI first: x6a init = b5 - x1 (x1r's LAST use; frees park slots)
    f32x4 x6a[4][3];
#pragma unroll
    for (int mt = 0; mt < 4; mt++) {
        f32x4 b = *(const f32x4*)(ws + B5 + mt * 16 + qd * 4);
        half8 nI = gfragH(wl, W_NI + mt * 512);
#pragma unroll
        for (int pt = 0; pt < 3; pt++)
            x6a[mt][pt] = MFMAH(nI, x1r[mt >> 1][pt], b);
    }

    // ===== D =====  two mt-halves; park xdf into the freed x1 slots
#pragma unroll
    for (int h = 0; h < 2; h++) {
        f32x4 accD[2][3];
#pragma unroll
        for (int m2 = 0; m2 < 2; m2++) {
            f32x4 b = *(const f32x4*)(ws + BD + (h * 2 + m2) * 16 + qd * 4);
            accD[m2][0] = b; accD[m2][1] = b; accD[m2][2] = b;
        }
#pragma unroll
        for (int m2 = 0; m2 < 2; m2++) {
            int mt = h * 2 + m2;
            half8 wh = gfragH(wl, W_D + mt * 1024);
            half8 wo = gfragH(wl, W_D + mt * 1024 + 512);
#pragma unroll
            for (int pt = 0; pt < 3; pt++) {
                accD[m2][pt] = MFMAH(wh, x4f[pt], accD[m2][pt]);
                accD[m2][pt] = MFMAH(wo, x4f[pt], accD[m2][pt]);
            }
        }
#pragma unroll
        for (int pt = 0; pt < 3; pt++)
            st16(xpark + h * 768 + pt * 256, packB(accD[0][pt], accD[1][pt]));
    }

    // ===== h4/h5 chunks: xdf re-read per chunk via opaque pointer =====
#pragma unroll
    for (int c = 0; c < 4; c++) {
        const unsigned int* xr = xpark;
        asm volatile("" : "+v"(xr));   // opaque: block LICM hoist of the reads
        half8 xd[2][3];
#pragma unroll
        for (int kt = 0; kt < 2; kt++)
#pragma unroll
            for (int pt = 0; pt < 3; pt++)
                xd[kt][pt] = ld16(xr + kt * 768 + pt * 256);
        f32x4 acc5[2][3];
#pragma unroll
        for (int mt2 = 0; mt2 < 2; mt2++) {
            f32x4 b = *(const f32x4*)(ws + B4 + c * 32 + mt2 * 16 + qd * 4);
            acc5[mt2][0] = b; acc5[mt2][1] = b; acc5[mt2][2] = b;
        }
#pragma unroll
        for (int kt = 0; kt < 2; kt++)
#pragma unroll
            for (int mt2 = 0; mt2 < 2; mt2++) {
                half8 w = gfragH(wl, W_H4C0 + c * 4096 + (mt2 * 2 + kt) * 512);
#pragma unroll
                for (int pt = 0; pt < 3; pt++)
                    acc5[mt2][pt] = MFMAH(w, xd[kt][pt], acc5[mt2][pt]);
            }
        half8 chf[3];
#pragma unroll
        for (int pt = 0; pt < 3; pt++)
            chf[pt] = packB(tanh4(acc5[0][pt]), tanh4(acc5[1][pt]));
#pragma unroll
        for (int mt = 0; mt < 4; mt++) {
            half8 w = gfragH(wl, W_H5C0 + c * 4096 + mt * 512);
#pragma unroll
            for (int pt = 0; pt < 3; pt++)
                x6a[mt][pt] = MFMAH(w, chf[pt], x6a[mt][pt]);
        }
    }

    // ===== out =====
    f32x4 accO[3];
    {
        f32x4 b = *(const f32x4*)(ws + BOUT + qd * 4);
        accO[0] = b; accO[1] = b; accO[2] = b;
    }
#pragma unroll
    for (int kt = 0; kt < 2; kt++) {
        half8 w = gfragH(wl, W_OUT + kt * 512);
#pragma unroll
        for (int pt = 0; pt < 3; pt++) {
            half8 x6f = packB(x6a[2 * kt][pt], x6a[2 * kt + 1][pt]);
            accO[pt] = MFMAH(w, x6f, accO[pt]);
        }
    }
    // C rows = output channels (0..2 live in qd==0, r<3); cols = pixels.
    if (qd == 0) {
#pragma unroll
        for (int pt = 0; pt < 3; pt++) {
            int p = p0 + wv * 48 + pt * 16 + mcol;
#pragma unroll
            for (int r = 0; r < 3; r++)
                out[(bb * 3 + r) * HW + p] = lrelu(accO[pt][r]);
        }
    }
}

extern "C" void kernel_launch(void* const* d_in, const int* in_sizes, int n_in,
                              void* d_out, int out_size, void* d_ws, size_t ws_size,
                              hipStream_t stream)
{
    const float* xin = (const float*)d_in[0];
    float* ws = (float*)d_ws;

    setup_all<<<75, 256, 0, stream>>>(
        (const float*)d_in[1],  (const float*)d_in[2],   // input
        (const float*)d_in[3],  (const float*)d_in[4],   // h1
        (const float*)d_in[5],  (const float*)d_in[6],   // h2
        (const float*)d_in[7],  (const float*)d_in[8],   // h3
        (const float*)d_in[9],  (const float*)d_in[10],  // h4
        (const float*)d_in[11], (const float*)d_in[12],  // h5
        (const float*)d_in[13], (const float*)d_in[14],  // out
        (const float*)d_in[15], (const float*)d_in[16],  // e1
        (const float*)d_in[17], (const float*)d_in[18],  // e2
        (const float*)d_in[19], (const float*)d_in[20],  // e3
        (const float*)d_in[21], (const float*)d_in[22],  // f1
        (const float*)d_in[23], (const float*)d_in[24],  // f2
        (const float*)d_in[25], (const float*)d_in[26],  // f3
        (const float*)d_in[27], (const float*)d_in[28],  // d1
        (const float*)d_in[29], (const float*)d_in[30],  // d2
        (const float*)d_in[31], (const float*)d_in[32],  // d3
        ws);

    fused_mfma<<<NBLK, 256, 0, stream>>>(xin, ws, (float*)d_out);
}